// Round 10
// baseline (486.499 us; speedup 1.0000x reference)
//
#include <hip/hip_runtime.h>
#include <math.h>

// Problem constants
#define NB 2
#define NC 256
#define CG 16
#define HH 192
#define WW 192
#define HO 190
#define PP 144

typedef float v2f __attribute__((ext_vector_type(2)));

// LDS: 7348 floats = 29392 B.
// Band area: 35 rows x 196 (row r at r*196: [0..3]=pads always zero,
//   [4..195]=data). Window reads at r*196 + wbase + d (wbase=2+v2+DJ0):
//   left spill -> own pads [2,3], right spill -> next row's pads [0,1].
// Epilogue: edge rows 0..11 (same layout), row 12 = permanent zero guard
//   (slots [0,1] catch edge-row-11 right spill), red[192][25] at 2548.
#define SMEM_FLOATS 7348

// ---------------------------------------------------------------------------
// Kernel 1: correlation-decomposed Gram. Same per-accumulator FMA values and
// order as rounds 1-9 -> bit-identical gram.
// THIS ROUND: offset-split across thread halves. 384-thread blocks; threads
// 0-191 own dj{0,1,2} (15 offsets) of column v2, threads 192-383 own dj{3,4}
// (10 offsets). Halves per-thread state (~75 live regs: 30 mid2 + 18 win +
// 12 cab) -> fits the (384,3) VGPR cap (~85, empirical cap=256/minwaves) ->
// 6 waves/SIMD = 24 waves/CU (was 128 VGPR -> 4/SIMD, measured 5 waves/CU,
// per-wave issue duty ~8%: latency-bound). LDS reads per column stay 5/step
// (3+2) unlike r7's channel-split (which doubled them). (384,3) is FEASIBLE
// (2 blocks x 59KB LDS), avoiding the r3/r4 infeasible-hint regalloc poison.
// Structure otherwise = r8/r9 winner: 6-phase pipelined window ring, 35-row
// chained bands, 6-deep global ring, strength-reduced addressing, pk-fma,
// XCD-clustered swizzle.
// ---------------------------------------------------------------------------
__global__ __launch_bounds__(384, 3) void gram_kernel(const float* __restrict__ x,
                                                      double* __restrict__ gram)
{
    __shared__ float smem[SMEM_FLOATS];
    float* const red_s = smem + 2548;

    const int v = threadIdx.x;                // 0..383
    const int half = (v >= 192) ? 1 : 0;      // 0: dj 0..2, 1: dj 3..4
    const int v2 = v - half * 192;            // column 0..191
    const int wbase = 2 + v2 + half * 3;      // LDS col base incl. DJ0

    // XCD-clustered decode: bid%8 = intended XCD; half-group hg (36 blocks)
    // pinned to XCD hg%8. Bijective over 2304 blocks.
    const int bid = blockIdx.x;
    const int vx = bid & 7;
    const int tq = bid >> 3;                  // 0..287
    const int idxw = tq / 36;                 // 0..7
    const int rr0 = tq - idxw * 36;           // 0..35
    const int hg = idxw * 8 + vx;             // 0..63
    const int bg = hg >> 1;
    int r = rr0 + 36 * (hg & 1);              // 0..71
    int c2 = 0;
    while (r >= (c2 + 2) / 2) { r -= (c2 + 2) / 2; ++c2; }
    const int c1a = 2 * r;
    int c1b = 2 * r + 1;
    const bool bval = (c1b <= c2);
    if (!bval) c1b = c2;
    const int b = bg >> 4, g = bg & 15;

    const float* __restrict__ xa  = x + ((size_t)(b * NC + g * CG + c1a)) * (HH * WW);
    const float* __restrict__ xb  = x + ((size_t)(b * NC + g * CG + c1b)) * (HH * WW);
    const float* __restrict__ x2g = x + ((size_t)(b * NC + g * CG + c2 )) * (HH * WW);

    // zero pad slots [0..3] of rows 0..36 once; staging never writes pads.
    if (v < 148) smem[(v >> 2) * 196 + (v & 3)] = 0.f;

    // mid2[kk*ND + d]: ND=3 for half0 (dj=d), ND=2 for half1 (dj=3+d).
    // Shared array sized for the larger half; half1 leaves 10..14 unused.
    v2f mid2[15];
#pragma unroll
    for (int o = 0; o < 15; ++o) mid2[o] = (v2f){0.f, 0.f};

    float win[6][3];                          // slot s: local row L, L%6==s
    v2f cab[6];                               // cab[(u-2)%6] = {xa,xb} row u
#pragma unroll
    for (int k = 0; k < 6; ++k)               // rows 2..7
        cab[k] = (v2f){xa[(size_t)(2 + k) * WW + v2], xb[(size_t)(2 + k) * WW + v2]};

    const float* pa = xa + (size_t)8 * WW + v2;   // refill base (row ubase+6)
    const float* pb = xb + (size_t)8 * WW + v2;
    int lds_off;                              // float idx of WPF row col-base

// One u-step. P = phase = LS%6 (compile-time). Consumes cab[P] (row u) and
// win slots (P+kk)%6 (local rows LS..LS+4, loaded >=1 step earlier).
//   WPF: window row local LS+5 -> slot (P+5)%6 via running lds_off;
//   GPF: cab[P] <- rows at pa/pb[P*WW] (row ubase+6+P, consumed 6 steps on).
#define USTEP6(P, WPF, GPF, ND)                                               \
    {                                                                         \
        const v2f ab = cab[(P)];                                              \
        if (GPF) cab[(P)] = (v2f){pa[(P) * WW], pb[(P) * WW]};                \
        if (WPF) {                                                            \
            _Pragma("unroll")                                                 \
            for (int d = 0; d < (ND); ++d)                                    \
                win[((P) + 5) % 6][d] = smem[lds_off + d];                    \
        }                                                                     \
        lds_off += 196;                                                       \
        _Pragma("unroll")                                                     \
        for (int kk = 0; kk < 5; ++kk) {                                      \
            _Pragma("unroll")                                                 \
            for (int d = 0; d < (ND); ++d) {                                  \
                const float xv = win[((P) + kk) % 6][d];                      \
                mid2[kk * (ND) + d] = __builtin_elementwise_fma(              \
                    ab, (v2f){xv, xv}, mid2[kk * (ND) + d]);                  \
            }                                                                 \
        }                                                                     \
    }

// Per-band compute for one half (ND = its dj count). Band-0 prologue loads
// locals 0..4 into slots 0..4; thereafter step LS=29's WPF (local 34 = next
// band's local 4) chains bands without a prologue.
#define BANDBODY(ND)                                                          \
    {                                                                         \
        if (band == 0) {                                                      \
            _Pragma("unroll")                                                 \
            for (int k = 0; k < 5; ++k)                                       \
                _Pragma("unroll")                                             \
                for (int d = 0; d < (ND); ++d)                                \
                    win[k][d] = smem[k * 196 + wbase + d];                    \
        }                                                                     \
        if (full) {                                                           \
            for (int it = 0; it < 5; ++it) {                                  \
                USTEP6(0,1,1,ND) USTEP6(1,1,1,ND) USTEP6(2,1,1,ND)            \
                USTEP6(3,1,1,ND) USTEP6(4,1,1,ND) USTEP6(5,1,1,ND)            \
                pa += 6 * WW; pb += 6 * WW;                                   \
            }                                                                 \
        } else {                                                              \
            USTEP6(0,1,1,ND) USTEP6(1,1,1,ND) USTEP6(2,1,0,ND)                \
            USTEP6(3,1,0,ND) USTEP6(4,1,0,ND) USTEP6(5,1,0,ND)                \
            USTEP6(0,1,0,ND) USTEP6(1,0,0,ND)                                 \
        }                                                                     \
    }

    // 7 bands: 6 x 30 steps (u=2..181, stage 35 rows) + tail 8 steps
    // (u=182..189, stage 12 rows: abs 180..191).
    for (int band = 0; band < 7; ++band) {
        const bool full = (band < 6);
        const int u0 = 2 + band * 30;
        const int row0 = u0 - 2;
        const int limit = (full ? 35 : 12) * 48;   // float4 slots
        __syncthreads();
        for (int it = 0; it < (full ? 5 : 2); ++it) {
            const int idx = it * 384 + v;
            if (idx < limit) {
                const int rr2 = idx / 48;
                const int c4 = (idx - rr2 * 48) * 4;
                const float4 val = *(const float4*)(x2g + (size_t)(row0 + rr2) * WW + c4);
                *(float4*)(&smem[rr2 * 196 + 4 + c4]) = val;
            }
        }
        __syncthreads();
        lds_off = 5 * 196 + wbase;            // local row 5, this band

        if (!half) BANDBODY(3) else BANDBODY(2)
    }
#undef USTEP6
#undef BANDBODY

    // stage edge buffer: buf i<6 -> abs row i-2 (OOB zero), i>=6 -> 188+(i-6).
    // Halves stage 6 rows each (no overlap). Row 12 = zero guard; red_s@2548.
    __syncthreads();
#pragma unroll
    for (int ii = 0; ii < 6; ++ii) {
        const int i = half * 6 + ii;
        const int ar = (i < 6) ? (i - 2) : (188 + i - 6);
        const float val = (ar >= 0 && ar <= 191) ? x2g[(size_t)ar * WW + v2] : 0.f;
        smem[i * 196 + 4 + v2] = val;
    }
    __syncthreads();

    double* const gp = gram + (size_t)bg * (PP * PP);

// Epilogue per-half write of corrected windows into red_s[v2*25 + o],
// o = k*5 + DJ0 + d. Halves cover disjoint o; union = 25.
#define EPIWRITE(ND, DJ0)                                                     \
    _Pragma("unroll")                                                         \
    for (int k = 0; k < 5; ++k) {                                             \
        const int bufa = (ra < 2) ? (ra + k) : (ra + k - 184);                \
        const int bufb = (rb < 2) ? (rb + k) : (rb + k - 184);                \
        _Pragma("unroll")                                                     \
        for (int d = 0; d < (ND); ++d) {                                      \
            const v2f m = mid2[k * (ND) + d];                                 \
            float cw = (c == 0) ? m.x : m.y;                                  \
            cw = fmaf(xra, smem[bufa * 196 + wbase + d], cw);                 \
            cw = fmaf(xrb, smem[bufb * 196 + wbase + d], cw);                 \
            red_s[v2 * 25 + k * 5 + (DJ0) + d] = cw;                          \
        }                                                                     \
    }

#pragma unroll
    for (int i1 = 0; i1 < 3; ++i1) {
        const int ra = (i1 == 0) ? 0 : ((i1 == 1) ? 1 : 190);
        const int rb = (i1 == 0) ? 1 : ((i1 == 1) ? 190 : 191);
#pragma unroll
        for (int c = 0; c < 2; ++c) {
            const float* __restrict__ xc = (c == 0) ? xa : xb;
            const float xra = xc[(size_t)ra * WW + v2];
            const float xrb = xc[(size_t)rb * WW + v2];
            if (!half) EPIWRITE(3, 0) else EPIWRITE(2, 3)
            __syncthreads();
            float e0 = 0.f, e1 = 0.f, e190 = 0.f, e191 = 0.f;
            if (v < 25) {
                e0   = red_s[0 * 25 + v];
                e1   = red_s[1 * 25 + v];
                e190 = red_s[190 * 25 + v];
                e191 = red_s[191 * 25 + v];
            }
            __syncthreads();
            // tree reduce over columns: 192 -> 96 -> ... -> 3 (stride 25: conflict-free)
#pragma unroll
            for (int s = 96; s >= 3; s >>= 1) {
                for (int idx = v; idx < s * 25; idx += 384) {
                    const int vv = idx / 25, o = idx - vv * 25;
                    red_s[vv * 25 + o] += red_s[(vv + s) * 25 + o];
                }
                __syncthreads();
            }
            if (v < 25 && (c == 0 || bval)) {
                const int di = v / 5 - 2, dj = v - (v / 5) * 5 - 2;
                const int i2 = i1 + di;
                if (i2 >= 0 && i2 <= 2) {
                    const float S = red_s[0 * 25 + v] + red_s[1 * 25 + v] + red_s[2 * 25 + v];
                    const int c1 = (c == 0) ? c1a : c1b;
#pragma unroll
                    for (int j1 = 0; j1 < 3; ++j1) {
                        const int j2 = j1 + dj;
                        if (j2 < 0 || j2 > 2) continue;
                        const float W = S - ((j1 == 0) ? (e190 + e191)
                                          : (j1 == 1) ? (e0 + e191)
                                                      : (e0 + e1));
                        const int p = c1 * 9 + i1 * 3 + j1;
                        const int q = c2 * 9 + i2 * 3 + j2;
                        gp[p * PP + q] = (double)W;
                        if (c1 != c2) gp[q * PP + p] = (double)W;
                    }
                }
            }
            __syncthreads();   // red reused by next (i1,c)
        }
    }
#undef EPIWRITE
}

// ---------------------------------------------------------------------------
// Kernel 2: per-group argmin (f64 d2, first-min tiebreak), bincount over both
// batches, stable top-3 (smallest index on count ties, matching lax.top_k).
// ---------------------------------------------------------------------------
__global__ __launch_bounds__(320) void topk_kernel(const double* __restrict__ gram,
                                                   float* __restrict__ pf,
                                                   int* __restrict__ pi)
{
    const int g = blockIdx.x;
    __shared__ double sdiag[2][PP];
    __shared__ int counts[PP];
    const int tid = threadIdx.x;
    if (tid < PP) counts[tid] = 0;
    if (tid < 2 * PP) {
        const int b = tid / PP, p = tid % PP;
        const double* gb = gram + (size_t)(b * 16 + g) * (PP * PP);
        sdiag[b][p] = gb[p * PP + p];
    }
    __syncthreads();
    if (tid < 2 * PP) {
        const int b = tid / PP, p = tid % PP;
        const double* row = gram + ((size_t)(b * 16 + g) * PP + p) * PP;
        const double sp = sdiag[b][p];
        double best = 1e300;
        int bi = 0;
        for (int q = 0; q < PP; ++q) {
            if (q == p) continue;
            const double d2 = sp + sdiag[b][q] - 2.0 * row[q];
            if (d2 < best) { best = d2; bi = q; }   // strict < : first occurrence
        }
        atomicAdd(&counts[bi], 1);
    }
    __syncthreads();
    if (tid == 0) {
        int sel[3], cv[3];
        for (int o = 0; o < 3; ++o) {
            int bc = -1, bp = 0;
            for (int p = 0; p < PP; ++p) {
                bool taken = false;
                for (int u = 0; u < o; ++u) if (sel[u] == p) taken = true;
                if (!taken && counts[p] > bc) { bc = counts[p]; bp = p; } // > keeps lowest idx
            }
            sel[o] = bp; cv[o] = bc;
        }
        const int tot = cv[0] + cv[1] + cv[2];
        for (int o = 0; o < 3; ++o) {
            pf[g * 4 + o] = (float)cv[o];
            pi[g * 4 + o] = sel[o];
        }
        pf[g * 4 + 3] = (float)tot;
    }
}

// ---------------------------------------------------------------------------
// Kernel 3: fused scale->floor->fold stencil. t1,t2 are plain f32 muls
// (== __fmul_rn == reference). Division via f64 reciprocal-multiply:
// bit-exact (total<=288 => exact quotients >=2^-34 rel from any f32 rounding
// midpoint, exact ties impossible, f64 error <=2^-52 -> identical rounding).
// Interior and edge in separate kernels (no divergent waves).
// ---------------------------------------------------------------------------
template <bool EDGE>
__device__ __forceinline__ void motif_quad(const float* __restrict__ x,
                                           const float* __restrict__ pf,
                                           const int* __restrict__ pi,
                                           float* __restrict__ out,
                                           int b, int ch, int h, int w0)
{
    const int g = ch >> 4;
    const size_t base = ((size_t)(b * NC + ch)) * (HH * WW);
    const float4 xv4 = *(const float4*)(x + base + (size_t)h * WW + w0);
    const float xs[4] = {xv4.x, xv4.y, xv4.z, xv4.w};
    float acc[4] = {0.f, 0.f, 0.f, 0.f};
    const float total = pf[g * 4 + 3];
    const double invd = 1.0 / (double)total;

#pragma unroll
    for (int o = 0; o < 3; ++o) {
        const int p = pi[g * 4 + o];
        const float cff = pf[g * 4 + o];
        const int co = p / 9;
        const int kk = p - co * 9;
        const int io = kk / 3, jo = kk - (kk / 3) * 3;
        const float* Rb = x + ((size_t)(b * NC + g * CG + co)) * (HH * WW);
#pragma unroll
        for (int i = 0; i < 3; ++i) {
            const int ho = h - i;
            bool rowok = true;
            int hr = ho + io;
            if (EDGE) {
                rowok = (ho >= 0) && (ho < HO);
                hr = hr < 0 ? 0 : (hr > HH - 1 ? HH - 1 : hr);
            }
            const float* row = Rb + (size_t)hr * WW;
            float rv[6];
#pragma unroll
            for (int u = 0; u < 6; ++u) {
                int col = w0 - 2 + jo + u;
                if (EDGE) col = col < 0 ? 0 : (col > WW - 1 ? WW - 1 : col);
                rv[u] = row[col];
            }
#pragma unroll
            for (int j = 0; j < 3; ++j)
#pragma unroll
            for (int q = 0; q < 4; ++q) {
                const float r2 = rv[q - j + 2];
                const float t1 = xs[q] * r2;                  // == __fmul_rn
                const float t2 = t1 * cff;                    // == __fmul_rn
                const float qf = (float)((double)t2 * invd);  // == __fdiv_rn(t2,total)
                const float vfl = floorf(qf);
                if (EDGE) {
                    const int wo = w0 + q - j;
                    const bool ok = rowok && (wo >= 0) && (wo < HO);
                    acc[q] += ok ? vfl : 0.f;
                } else {
                    acc[q] += vfl;
                }
            }
        }
    }
    float4 ov = make_float4(acc[0], acc[1], acc[2], acc[3]);
    *(float4*)(out + base + (size_t)h * WW + w0) = ov;
}

// interior: h in [2,189], w4 in [1,46] -> no clamps/masks anywhere.
__global__ __launch_bounds__(256) void out_interior(const float* __restrict__ x,
                                                    const float* __restrict__ pf,
                                                    const int* __restrict__ pi,
                                                    float* __restrict__ out)
{
    const int gid = blockIdx.x * 256 + threadIdx.x;
    const int w4i = gid % 46;
    int t = gid / 46;
    const int h = 2 + t % 188; t /= 188;
    const int ch = t & 255;
    const int b = t >> 8;
    motif_quad<false>(x, pf, pi, out, b, ch, h, (w4i + 1) * 4);
}

// edge: 568 quads per (b,ch): h in {0,1,190,191} x all 48 w4, plus
// h in [2,189] x w4 in {0,47}.
__global__ __launch_bounds__(256) void out_edge(const float* __restrict__ x,
                                                const float* __restrict__ pf,
                                                const int* __restrict__ pi,
                                                float* __restrict__ out)
{
    const int gid = blockIdx.x * 256 + threadIdx.x;
    const int e = gid % 568;
    int t = gid / 568;
    const int ch = t & 255;
    const int b = t >> 8;
    int h, w4;
    if (e < 192) {
        const int hs = e / 48;
        h = (hs < 2) ? hs : 188 + hs;         // 0,1,190,191
        w4 = e % 48;
    } else {
        const int e2 = e - 192;
        h = 2 + (e2 >> 1);
        w4 = (e2 & 1) ? 47 : 0;
    }
    motif_quad<true>(x, pf, pi, out, b, ch, h, w4 * 4);
}

// ---------------------------------------------------------------------------
extern "C" void kernel_launch(void* const* d_in, const int* in_sizes, int n_in,
                              void* d_out, int out_size, void* d_ws, size_t ws_size,
                              hipStream_t stream)
{
    const float* x = (const float*)d_in[0];
    float* out = (float*)d_out;

    double* gram = (double*)d_ws;
    const size_t gram_bytes = (size_t)32 * PP * PP * sizeof(double); // 5,308,416 B
    float* pf = (float*)((char*)d_ws + gram_bytes);
    int* pi = (int*)((char*)d_ws + gram_bytes + 256);

    gram_kernel<<<2304, 384, 0, stream>>>(x, gram);
    topk_kernel<<<16, 320, 0, stream>>>(gram, pf, pi);
    out_interior<<<17296, 256, 0, stream>>>(x, pf, pi, out);  // 2*256*188*46/256
    out_edge<<<1136, 256, 0, stream>>>(x, pf, pi, out);       // 2*256*568/256
}

// Round 11
// 472.203 us; speedup vs baseline: 1.0303x; 1.0303x over previous
//
#include <hip/hip_runtime.h>
#include <math.h>

// Problem constants
#define NB 2
#define NC 256
#define CG 16
#define HH 192
#define WW 192
#define HO 190
#define PP 144

typedef float v2f __attribute__((ext_vector_type(2)));

// LDS: 7348 floats = 29392 B.
// Band area: 35 rows x 196 (row r at r*196: [0..3]=pads always zero,
//   [4..195]=data). Window reads at r*196 + 2+v+dj: left spill -> own pads
//   [2,3], right spill -> next row's pads [0,1] (never written by staging).
// Epilogue: edge rows 0..11 (same layout), row 12 = permanent zero guard
//   (slots [0,1] catch edge-row-11 right spill), red[192][25] at 2548.
#define SMEM_FLOATS 7348

// ---------------------------------------------------------------------------
// Kernel 1: correlation-decomposed Gram, U-SPLIT: each (bg,c2,c1-pair) is
// covered by TWO blocks (sblk 0/1), each handling 94 of the 188 u-steps
// (3 x 30-step bands + 4-step tail). Partial window-sums are linear, so each
// block tree-reduces its partial W and f64-atomicAdds into gram: exactly 2
// contributions per entry (IEEE 2-operand add is commutative -> result is
// order-independent -> deterministic). Edge-row corrections applied by the
// sblk==0 block only. Rationale: r2-r10 all plateaued at VALUBusy 26-34%
// with ~16% occupancy regardless of VGPR/threads -> blocks run in barrier
// LOCKSTEP; independent half-range blocks at staggered phases overlap each
// other's staging/latency. Same-data pair is 2304 apart (2304%8==0 -> same
// XCD slot) for L2 reuse. Internals = r9 winner: 192 thr, (192,2), 6-phase
// pipelined window ring, 6-deep global ring, pk-fma, strength-reduced
// addressing, XCD-clustered swizzle. Gram is no longer bit-identical to
// r1-r9 (u-halves summed in f64), but selection rests on ranking robustness
// (established since r0: absmax 0 with different-order gram; f64 margins).
// ---------------------------------------------------------------------------
__global__ __launch_bounds__(192, 2) void gram_kernel(const float* __restrict__ x,
                                                      double* __restrict__ gram)
{
    __shared__ float smem[SMEM_FLOATS];
    float* const red_s = smem + 2548;

    const int v = threadIdx.x;                // column 0..191

    // u-split: blocks [0,2304) = sblk 0 (u 2..95), [2304,4608) = sblk 1
    // (u 96..189). Inner decode identical to r9 on rb in [0,2304).
    const int bid = blockIdx.x;
    const int sblk = (bid >= 2304) ? 1 : 0;
    const int rb = bid - sblk * 2304;
    const int ustart = 2 + sblk * 94;

    // XCD-clustered decode: rb%8 = intended XCD; half-group hg (36 blocks)
    // pinned to XCD hg%8. Bijective over 2304.
    const int vx = rb & 7;
    const int tq = rb >> 3;                   // 0..287
    const int idxw = tq / 36;                 // 0..7
    const int rr0 = tq - idxw * 36;           // 0..35
    const int hg = idxw * 8 + vx;             // 0..63
    const int bg = hg >> 1;
    int r = rr0 + 36 * (hg & 1);              // 0..71
    int c2 = 0;
    while (r >= (c2 + 2) / 2) { r -= (c2 + 2) / 2; ++c2; }
    const int c1a = 2 * r;
    int c1b = 2 * r + 1;
    const bool bval = (c1b <= c2);
    if (!bval) c1b = c2;
    const int b = bg >> 4, g = bg & 15;

    const float* __restrict__ xa  = x + ((size_t)(b * NC + g * CG + c1a)) * (HH * WW);
    const float* __restrict__ xb  = x + ((size_t)(b * NC + g * CG + c1b)) * (HH * WW);
    const float* __restrict__ x2g = x + ((size_t)(b * NC + g * CG + c2 )) * (HH * WW);

    // zero pad slots [0..3] of rows 0..36 once; staging never writes pads.
    if (v < 148) smem[(v >> 2) * 196 + (v & 3)] = 0.f;

    v2f mid2[25];                             // .x = chan c1a, .y = chan c1b
#pragma unroll
    for (int o = 0; o < 25; ++o) mid2[o] = (v2f){0.f, 0.f};

    float win[6][5];                          // slot s: block-local row L, L%6==s
    v2f cab[6];                               // cab[(u-ustart)%6] = {xa,xb} row u
#pragma unroll
    for (int k = 0; k < 6; ++k)               // rows ustart..ustart+5
        cab[k] = (v2f){xa[(size_t)(ustart + k) * WW + v],
                       xb[(size_t)(ustart + k) * WW + v]};

    const float* pa = xa + (size_t)(ustart + 6) * WW + v;  // refill base
    const float* pb = xb + (size_t)(ustart + 6) * WW + v;
    int lds_off;                              // float idx of WPF row start

// One u-step. P = phase = LS%6 (LS = block-local step, band-local lbase%6==0).
// Consumes cab[P] (row u) and win slots (P+kk)%6 (band-local rows LS..LS+4,
// loaded >=1 step earlier).
//   WPF: window row band-local LS+5 -> slot (P+5)%6 via running lds_off;
//   GPF: cab[P] <- rows at pa/pb[P*WW] (consumed 6 steps later).
#define USTEP6(P, WPF, GPF)                                                   \
    {                                                                         \
        const v2f ab = cab[(P)];                                              \
        if (GPF) cab[(P)] = (v2f){pa[(P) * WW], pb[(P) * WW]};                \
        if (WPF) {                                                            \
            const float* wr = &smem[lds_off];                                 \
            _Pragma("unroll")                                                 \
            for (int dj = 0; dj < 5; ++dj)                                    \
                win[((P) + 5) % 6][dj] = wr[dj];                              \
        }                                                                     \
        lds_off += 196;                                                       \
        _Pragma("unroll")                                                     \
        for (int kk = 0; kk < 5; ++kk) {                                      \
            _Pragma("unroll")                                                 \
            for (int dj = 0; dj < 5; ++dj) {                                  \
                const float xv = win[((P) + kk) % 6][dj];                     \
                mid2[kk * 5 + dj] = __builtin_elementwise_fma(                \
                    ab, (v2f){xv, xv}, mid2[kk * 5 + dj]);                    \
            }                                                                 \
        }                                                                     \
    }

    // 4 bands: 3 x 30 steps (stage 35 rows) + 4-step tail (stage 8 rows).
    // Step LS=29's WPF loads local 34 = next band's local 4 -> bands chain;
    // only band 0 has a prologue. Full-band GPF max row: ustart+95 (<=97 for
    // sblk0, <=191 for sblk1: in bounds). Tail GPF=0 (sblk1 would be OOB).
    for (int band = 0; band < 4; ++band) {
        const bool full = (band < 3);
        const int u0 = ustart + band * 30;
        const int row0 = u0 - 2;
        const int limit = (full ? 35 : 8) * 48;    // float4 slots
        __syncthreads();
        for (int it = 0; it < (full ? 9 : 2); ++it) {
            const int idx = it * 192 + v;
            if (idx < limit) {
                const int rr2 = idx / 48;
                const int c4 = (idx - rr2 * 48) * 4;
                const float4 val = *(const float4*)(x2g + (size_t)(row0 + rr2) * WW + c4);
                *(float4*)(&smem[rr2 * 196 + 4 + c4]) = val;
            }
        }
        __syncthreads();
        if (band == 0) {
            // only prologue of the block: locals 0..4 -> slots 0..4
#pragma unroll
            for (int k = 0; k < 5; ++k)
#pragma unroll
            for (int dj = 0; dj < 5; ++dj)
                win[k][dj] = smem[k * 196 + 2 + v + dj];
        }
        lds_off = 5 * 196 + 2 + v;            // band-local row 5

        if (full) {
            for (int it = 0; it < 5; ++it) {  // rolled: small hot body
                USTEP6(0, 1, 1) USTEP6(1, 1, 1) USTEP6(2, 1, 1)
                USTEP6(3, 1, 1) USTEP6(4, 1, 1) USTEP6(5, 1, 1)
                pa += 6 * WW; pb += 6 * WW;   // next group's refill base
            }
        } else {
            // tail: steps 0..3 (u = ustart+90..ustart+93); WPF locals 5,6,7
            USTEP6(0, 1, 0) USTEP6(1, 1, 0) USTEP6(2, 1, 0) USTEP6(3, 0, 0)
        }
    }
#undef USTEP6

    // stage edge buffer (sblk 0 only; sblk 1's epilogue never reads it):
    // buf i<6 -> abs row i-2 (OOB zero), i>=6 -> 188+(i-6). Row 12 = zero
    // guard (pads catch edge-row-11 right spill); red_s at 2548.
    __syncthreads();
    if (sblk == 0) {
        for (int i = 0; i < 12; ++i) {
            const int ar = (i < 6) ? (i - 2) : (188 + i - 6);
            const float val = (ar >= 0 && ar <= 191) ? x2g[(size_t)ar * WW + v] : 0.f;
            smem[i * 196 + 4 + v] = val;
        }
    }
    __syncthreads();

    double* const gp = gram + (size_t)bg * (PP * PP);

#pragma unroll
    for (int i1 = 0; i1 < 3; ++i1) {
        const int ra = (i1 == 0) ? 0 : ((i1 == 1) ? 1 : 190);
        const int rb2 = (i1 == 0) ? 1 : ((i1 == 1) ? 190 : 191);
#pragma unroll
        for (int c = 0; c < 2; ++c) {
            const float* __restrict__ xc = (c == 0) ? xa : xb;
            // corrected windows: mid partial (+ edge corrections, sblk0 only)
            if (sblk == 0) {
                const float xra = xc[(size_t)ra * WW + v];
                const float xrb = xc[(size_t)rb2 * WW + v];
#pragma unroll
                for (int k = 0; k < 5; ++k) {
                    const int bufa = (ra < 2) ? (ra + k) : (ra + k - 184);
                    const int bufb = (rb2 < 2) ? (rb2 + k) : (rb2 + k - 184);
#pragma unroll
                    for (int dj = 0; dj < 5; ++dj) {
                        const int q = k * 5 + dj;
                        float cw = (c == 0) ? mid2[q].x : mid2[q].y;
                        cw = fmaf(xra, smem[bufa * 196 + 2 + v + dj], cw);
                        cw = fmaf(xrb, smem[bufb * 196 + 2 + v + dj], cw);
                        red_s[v * 25 + q] = cw;
                    }
                }
            } else {
#pragma unroll
                for (int k = 0; k < 5; ++k)
#pragma unroll
                for (int dj = 0; dj < 5; ++dj) {
                    const int q = k * 5 + dj;
                    red_s[v * 25 + q] = (c == 0) ? mid2[q].x : mid2[q].y;
                }
            }
            __syncthreads();
            float e0 = 0.f, e1 = 0.f, e190 = 0.f, e191 = 0.f;
            if (v < 25) {
                e0   = red_s[0 * 25 + v];
                e1   = red_s[1 * 25 + v];
                e190 = red_s[190 * 25 + v];
                e191 = red_s[191 * 25 + v];
            }
            __syncthreads();
            // tree reduce over columns: 192 -> 96 -> ... -> 3 (stride 25: conflict-free)
#pragma unroll
            for (int s = 96; s >= 3; s >>= 1) {
                for (int idx = v; idx < s * 25; idx += 192) {
                    const int vv = idx / 25, o = idx - vv * 25;
                    red_s[vv * 25 + o] += red_s[(vv + s) * 25 + o];
                }
                __syncthreads();
            }
            if (v < 25 && (c == 0 || bval)) {
                const int di = v / 5 - 2, dj = v - (v / 5) * 5 - 2;
                const int i2 = i1 + di;
                if (i2 >= 0 && i2 <= 2) {
                    const float S = red_s[0 * 25 + v] + red_s[1 * 25 + v] + red_s[2 * 25 + v];
                    const int c1 = (c == 0) ? c1a : c1b;
#pragma unroll
                    for (int j1 = 0; j1 < 3; ++j1) {
                        const int j2 = j1 + dj;
                        if (j2 < 0 || j2 > 2) continue;
                        const float W = S - ((j1 == 0) ? (e190 + e191)
                                          : (j1 == 1) ? (e0 + e191)
                                                      : (e0 + e1));
                        const int p = c1 * 9 + i1 * 3 + j1;
                        const int q = c2 * 9 + i2 * 3 + j2;
                        atomicAdd(&gp[p * PP + q], (double)W);
                        if (c1 != c2) atomicAdd(&gp[q * PP + p], (double)W);
                    }
                }
            }
            __syncthreads();   // red reused by next (i1,c)
        }
    }
}

// ---------------------------------------------------------------------------
// Kernel 2: per-group argmin (f64 d2, first-min tiebreak), bincount over both
// batches, stable top-3 (smallest index on count ties, matching lax.top_k).
// ---------------------------------------------------------------------------
__global__ __launch_bounds__(320) void topk_kernel(const double* __restrict__ gram,
                                                   float* __restrict__ pf,
                                                   int* __restrict__ pi)
{
    const int g = blockIdx.x;
    __shared__ double sdiag[2][PP];
    __shared__ int counts[PP];
    const int tid = threadIdx.x;
    if (tid < PP) counts[tid] = 0;
    if (tid < 2 * PP) {
        const int b = tid / PP, p = tid % PP;
        const double* gb = gram + (size_t)(b * 16 + g) * (PP * PP);
        sdiag[b][p] = gb[p * PP + p];
    }
    __syncthreads();
    if (tid < 2 * PP) {
        const int b = tid / PP, p = tid % PP;
        const double* row = gram + ((size_t)(b * 16 + g) * PP + p) * PP;
        const double sp = sdiag[b][p];
        double best = 1e300;
        int bi = 0;
        for (int q = 0; q < PP; ++q) {
            if (q == p) continue;
            const double d2 = sp + sdiag[b][q] - 2.0 * row[q];
            if (d2 < best) { best = d2; bi = q; }   // strict < : first occurrence
        }
        atomicAdd(&counts[bi], 1);
    }
    __syncthreads();
    if (tid == 0) {
        int sel[3], cv[3];
        for (int o = 0; o < 3; ++o) {
            int bc = -1, bp = 0;
            for (int p = 0; p < PP; ++p) {
                bool taken = false;
                for (int u = 0; u < o; ++u) if (sel[u] == p) taken = true;
                if (!taken && counts[p] > bc) { bc = counts[p]; bp = p; } // > keeps lowest idx
            }
            sel[o] = bp; cv[o] = bc;
        }
        const int tot = cv[0] + cv[1] + cv[2];
        for (int o = 0; o < 3; ++o) {
            pf[g * 4 + o] = (float)cv[o];
            pi[g * 4 + o] = sel[o];
        }
        pf[g * 4 + 3] = (float)tot;
    }
}

// ---------------------------------------------------------------------------
// Kernel 3: fused scale->floor->fold stencil. t1,t2 are plain f32 muls
// (== __fmul_rn == reference). Division via f64 reciprocal-multiply:
// bit-exact (total<=288 => exact quotients >=2^-34 rel from any f32 rounding
// midpoint, exact ties impossible, f64 error <=2^-52 -> identical rounding).
// Interior and edge in separate kernels (no divergent waves).
// ---------------------------------------------------------------------------
template <bool EDGE>
__device__ __forceinline__ void motif_quad(const float* __restrict__ x,
                                           const float* __restrict__ pf,
                                           const int* __restrict__ pi,
                                           float* __restrict__ out,
                                           int b, int ch, int h, int w0)
{
    const int g = ch >> 4;
    const size_t base = ((size_t)(b * NC + ch)) * (HH * WW);
    const float4 xv4 = *(const float4*)(x + base + (size_t)h * WW + w0);
    const float xs[4] = {xv4.x, xv4.y, xv4.z, xv4.w};
    float acc[4] = {0.f, 0.f, 0.f, 0.f};
    const float total = pf[g * 4 + 3];
    const double invd = 1.0 / (double)total;

#pragma unroll
    for (int o = 0; o < 3; ++o) {
        const int p = pi[g * 4 + o];
        const float cff = pf[g * 4 + o];
        const int co = p / 9;
        const int kk = p - co * 9;
        const int io = kk / 3, jo = kk - (kk / 3) * 3;
        const float* Rb = x + ((size_t)(b * NC + g * CG + co)) * (HH * WW);
#pragma unroll
        for (int i = 0; i < 3; ++i) {
            const int ho = h - i;
            bool rowok = true;
            int hr = ho + io;
            if (EDGE) {
                rowok = (ho >= 0) && (ho < HO);
                hr = hr < 0 ? 0 : (hr > HH - 1 ? HH - 1 : hr);
            }
            const float* row = Rb + (size_t)hr * WW;
            float rv[6];
#pragma unroll
            for (int u = 0; u < 6; ++u) {
                int col = w0 - 2 + jo + u;
                if (EDGE) col = col < 0 ? 0 : (col > WW - 1 ? WW - 1 : col);
                rv[u] = row[col];
            }
#pragma unroll
            for (int j = 0; j < 3; ++j)
#pragma unroll
            for (int q = 0; q < 4; ++q) {
                const float r2 = rv[q - j + 2];
                const float t1 = xs[q] * r2;                  // == __fmul_rn
                const float t2 = t1 * cff;                    // == __fmul_rn
                const float qf = (float)((double)t2 * invd);  // == __fdiv_rn(t2,total)
                const float vfl = floorf(qf);
                if (EDGE) {
                    const int wo = w0 + q - j;
                    const bool ok = rowok && (wo >= 0) && (wo < HO);
                    acc[q] += ok ? vfl : 0.f;
                } else {
                    acc[q] += vfl;
                }
            }
        }
    }
    float4 ov = make_float4(acc[0], acc[1], acc[2], acc[3]);
    *(float4*)(out + base + (size_t)h * WW + w0) = ov;
}

// interior: h in [2,189], w4 in [1,46] -> no clamps/masks anywhere.
__global__ __launch_bounds__(256) void out_interior(const float* __restrict__ x,
                                                    const float* __restrict__ pf,
                                                    const int* __restrict__ pi,
                                                    float* __restrict__ out)
{
    const int gid = blockIdx.x * 256 + threadIdx.x;
    const int w4i = gid % 46;
    int t = gid / 46;
    const int h = 2 + t % 188; t /= 188;
    const int ch = t & 255;
    const int b = t >> 8;
    motif_quad<false>(x, pf, pi, out, b, ch, h, (w4i + 1) * 4);
}

// edge: 568 quads per (b,ch): h in {0,1,190,191} x all 48 w4, plus
// h in [2,189] x w4 in {0,47}.
__global__ __launch_bounds__(256) void out_edge(const float* __restrict__ x,
                                                const float* __restrict__ pf,
                                                const int* __restrict__ pi,
                                                float* __restrict__ out)
{
    const int gid = blockIdx.x * 256 + threadIdx.x;
    const int e = gid % 568;
    int t = gid / 568;
    const int ch = t & 255;
    const int b = t >> 8;
    int h, w4;
    if (e < 192) {
        const int hs = e / 48;
        h = (hs < 2) ? hs : 188 + hs;         // 0,1,190,191
        w4 = e % 48;
    } else {
        const int e2 = e - 192;
        h = 2 + (e2 >> 1);
        w4 = (e2 & 1) ? 47 : 0;
    }
    motif_quad<true>(x, pf, pi, out, b, ch, h, w4 * 4);
}

// ---------------------------------------------------------------------------
extern "C" void kernel_launch(void* const* d_in, const int* in_sizes, int n_in,
                              void* d_out, int out_size, void* d_ws, size_t ws_size,
                              hipStream_t stream)
{
    const float* x = (const float*)d_in[0];
    float* out = (float*)d_out;

    double* gram = (double*)d_ws;
    const size_t gram_bytes = (size_t)32 * PP * PP * sizeof(double); // 5,308,416 B
    float* pf = (float*)((char*)d_ws + gram_bytes);
    int* pi = (int*)((char*)d_ws + gram_bytes + 256);

    // gram is accumulated via f64 atomicAdd (2 partials/entry) -> zero first
    hipMemsetAsync(gram, 0, gram_bytes, stream);

    gram_kernel<<<4608, 192, 0, stream>>>(x, gram);
    topk_kernel<<<16, 320, 0, stream>>>(gram, pf, pi);
    out_interior<<<17296, 256, 0, stream>>>(x, pf, pi, out);  // 2*256*188*46/256
    out_edge<<<1136, 256, 0, stream>>>(x, pf, pi, out);       // 2*256*568/256
}

// Round 12
// 420.713 us; speedup vs baseline: 1.1564x; 1.1224x over previous
//
#include <hip/hip_runtime.h>
#include <math.h>

// Problem constants
#define NB 2
#define NC 256
#define CG 16
#define HH 192
#define WW 192
#define HO 190
#define PP 144

typedef float v2f __attribute__((ext_vector_type(2)));

// LDS: 7348 floats = 29392 B.
// Band area: 35 rows x 196 (row r at r*196: [0..3]=pads always zero,
//   [4..195]=data, data col c at slot 4+c). Thread v's window = data cols
//   v-2..v+2 = slots v+2..v+6; b64 window reads use base bb=(v+2)&~1 (even ->
//   8B-aligned for ALL lanes), 6 floats bb..bb+5 = window positions i=0..5,
//   dj = i - p with p = v&1 (one garbage lane -> dummy accumulator lane).
//   Max spill: slots bb+5 <= 197 -> next row's pads [0,1] (always zero).
// Epilogue: edge rows 0..11 (same layout), row 12 = permanent zero guard,
//   red[192][25] at 2548.
#define SMEM_FLOATS 7348

// ---------------------------------------------------------------------------
// Kernel 1: correlation-decomposed Gram. Bit-identical per-accumulator FMA
// values/order vs rounds 1-9 (u-split of r11 REVERTED: halving per-block work
// at 2x blocks changed nothing -> demand-bound, not residency-bound).
// THIS ROUND: pk packing axis flipped channels -> dj-pairs.
//  - splat operand is now the per-step scalar a1/b1 (2 movs/step amortized
//    over 30 pk_fma) instead of 25 per-FMA {xv,xv} broadcasts (the suspected
//    hidden ~25 v_mov/step behind busy=94us vs 27us pk floor);
//  - window row read: 5 x ds_read_b32 -> 3 x ds_read_b64 (8B-aligned via
//    even base; adjacent lanes share addresses -> broadcast, conflict-free);
//  - dummy lane per pair-triple absorbs the 6th float (never read).
// Structure otherwise = r9: 192 thr, (192,2), 6-phase pipelined window ring,
// 35-row chained bands, 6-deep global ring, strength-reduced addressing,
// XCD-clustered swizzle, direct f64 stores (no atomics, no memset).
// ---------------------------------------------------------------------------
__global__ __launch_bounds__(192, 2) void gram_kernel(const float* __restrict__ x,
                                                      double* __restrict__ gram)
{
    __shared__ float smem[SMEM_FLOATS];
    float* const red_s = smem + 2548;

    const int v = threadIdx.x;                // column 0..191
    const int p = v & 1;                      // window parity: dj = i - p
    const int bb = (v + 2) & ~1;              // even b64 base slot

    // XCD-clustered decode: bid%8 = intended XCD; half-group hg (36 blocks)
    // pinned to XCD hg%8. Bijective over 2304 blocks.
    const int bid = blockIdx.x;
    const int vx = bid & 7;
    const int tq = bid >> 3;                  // 0..287
    const int idxw = tq / 36;                 // 0..7
    const int rr0 = tq - idxw * 36;           // 0..35
    const int hg = idxw * 8 + vx;             // 0..63
    const int bg = hg >> 1;
    int r = rr0 + 36 * (hg & 1);              // 0..71
    int c2 = 0;
    while (r >= (c2 + 2) / 2) { r -= (c2 + 2) / 2; ++c2; }
    const int c1a = 2 * r;
    int c1b = 2 * r + 1;
    const bool bval = (c1b <= c2);
    if (!bval) c1b = c2;
    const int b = bg >> 4, g = bg & 15;

    const float* __restrict__ xa  = x + ((size_t)(b * NC + g * CG + c1a)) * (HH * WW);
    const float* __restrict__ xb  = x + ((size_t)(b * NC + g * CG + c1b)) * (HH * WW);
    const float* __restrict__ x2g = x + ((size_t)(b * NC + g * CG + c2 )) * (HH * WW);

    // zero pad slots [0..3] of rows 0..36 once; staging never writes pads.
    if (v < 148) smem[(v >> 2) * 196 + (v & 3)] = 0.f;

    // accumulators: lanes = window positions (2*pr, 2*pr+1); dj = pos - p.
    v2f midA[15], midB[15];                   // [k*3 + pr]
#pragma unroll
    for (int o = 0; o < 15; ++o) { midA[o] = (v2f){0.f, 0.f}; midB[o] = (v2f){0.f, 0.f}; }

    v2f win[6][3];                            // slot s: local row L (L%6==s), 3 pairs
    float ca[6], cb[6];                       // ca[(u-2)%6] holds xa row u
#pragma unroll
    for (int k = 0; k < 6; ++k) {             // rows 2..7
        ca[k] = xa[(size_t)(2 + k) * WW + v];
        cb[k] = xb[(size_t)(2 + k) * WW + v];
    }

    const float* pa = xa + (size_t)8 * WW + v;   // refill base (row ubase+6)
    const float* pb = xb + (size_t)8 * WW + v;
    int lds_off;                              // float idx of WPF row b64 base

// One u-step. P = phase = LS%6 (compile-time). Consumes ca/cb[P] (row u) and
// win slots (P+kk)%6 (local rows LS..LS+4, loaded >=1 step earlier).
//   WPF: window row local LS+5 -> slot (P+5)%6: 3 x ds_read_b64;
//   GPF: ca/cb[P] <- rows at pa/pb[P*WW] (consumed 6 steps later).
#define USTEP6(P, WPF, GPF)                                                   \
    {                                                                         \
        const float a1 = ca[(P)];                                             \
        const float b1 = cb[(P)];                                             \
        if (GPF) { ca[(P)] = pa[(P) * WW]; cb[(P)] = pb[(P) * WW]; }          \
        if (WPF) {                                                            \
            _Pragma("unroll")                                                 \
            for (int pr = 0; pr < 3; ++pr)                                    \
                win[((P) + 5) % 6][pr] = *(const v2f*)(&smem[lds_off + 2 * pr]); \
        }                                                                     \
        lds_off += 196;                                                       \
        const v2f a2 = (v2f){a1, a1};                                         \
        const v2f b2 = (v2f){b1, b1};                                         \
        _Pragma("unroll")                                                     \
        for (int kk = 0; kk < 5; ++kk) {                                      \
            _Pragma("unroll")                                                 \
            for (int pr = 0; pr < 3; ++pr) {                                  \
                const v2f wv = win[((P) + kk) % 6][pr];                       \
                midA[kk * 3 + pr] = __builtin_elementwise_fma(a2, wv, midA[kk * 3 + pr]); \
                midB[kk * 3 + pr] = __builtin_elementwise_fma(b2, wv, midB[kk * 3 + pr]); \
            }                                                                 \
        }                                                                     \
    }

    // 7 bands: 6 x 30 steps (u=2..181, stage 35 rows) + tail 8 steps
    // (u=182..189, stage 12 rows). Step LS=29's WPF loads local 34 = next
    // band's local 4 -> bands chain; only band 0 has a prologue.
    for (int band = 0; band < 7; ++band) {
        const bool full = (band < 6);
        const int u0 = 2 + band * 30;
        const int row0 = u0 - 2;
        const int limit = (full ? 35 : 12) * 48;   // float4 slots
        __syncthreads();
        for (int it = 0; it < (full ? 9 : 3); ++it) {
            const int idx = it * 192 + v;
            if (idx < limit) {
                const int rr2 = idx / 48;
                const int c4 = (idx - rr2 * 48) * 4;
                const float4 val = *(const float4*)(x2g + (size_t)(row0 + rr2) * WW + c4);
                *(float4*)(&smem[rr2 * 196 + 4 + c4]) = val;
            }
        }
        __syncthreads();
        if (band == 0) {
            // only prologue of the kernel: locals 0..4 -> slots 0..4
#pragma unroll
            for (int k = 0; k < 5; ++k)
#pragma unroll
            for (int pr = 0; pr < 3; ++pr)
                win[k][pr] = *(const v2f*)(&smem[k * 196 + bb + 2 * pr]);
        }
        lds_off = 5 * 196 + bb;               // local row 5, this band

        if (full) {
            for (int it = 0; it < 5; ++it) {  // rolled: small hot body
                USTEP6(0, 1, 1) USTEP6(1, 1, 1) USTEP6(2, 1, 1)
                USTEP6(3, 1, 1) USTEP6(4, 1, 1) USTEP6(5, 1, 1)
                pa += 6 * WW; pb += 6 * WW;   // next group's refill base
            }
        } else {
            // steps 0..5 (u=182..187); GPF only P<=1 (rows 188,189)
            USTEP6(0, 1, 1) USTEP6(1, 1, 1) USTEP6(2, 1, 0)
            USTEP6(3, 1, 0) USTEP6(4, 1, 0) USTEP6(5, 1, 0)
            // steps 6,7 (u=188,189): phases 0,1; WPF for LS=6 (local 11)
            USTEP6(0, 1, 0) USTEP6(1, 0, 0)
        }
    }
#undef USTEP6

    // stage edge buffer: buf i<6 -> abs row i-2 (OOB zero), i>=6 -> 188+(i-6).
    // Row 12 = zero guard; red_s at 2548.
    __syncthreads();
    for (int i = 0; i < 12; ++i) {
        const int ar = (i < 6) ? (i - 2) : (188 + i - 6);
        const float val = (ar >= 0 && ar <= 191) ? x2g[(size_t)ar * WW + v] : 0.f;
        smem[i * 196 + 4 + v] = val;
    }
    __syncthreads();

    double* const gp = gram + (size_t)bg * (PP * PP);

#pragma unroll
    for (int i1 = 0; i1 < 3; ++i1) {
        const int ra = (i1 == 0) ? 0 : ((i1 == 1) ? 1 : 190);
        const int rb = (i1 == 0) ? 1 : ((i1 == 1) ? 190 : 191);
#pragma unroll
        for (int c = 0; c < 2; ++c) {
            const float* __restrict__ xc = (c == 0) ? xa : xb;
            const float xra = xc[(size_t)ra * WW + v];
            const float xrb = xc[(size_t)rb * WW + v];
#pragma unroll
            for (int k = 0; k < 5; ++k) {
                const int bufa = (ra < 2) ? (ra + k) : (ra + k - 184);
                const int bufb = (rb < 2) ? (rb + k) : (rb + k - 184);
#pragma unroll
                for (int dj = 0; dj < 5; ++dj) {
                    // mid value for (c,k,dj): window position i = dj + p.
                    // Both parity variants use compile-time register indices;
                    // runtime select on p (avoids scratch, rule: no runtime
                    // indexing of register arrays).
                    float ve, vo;
                    {   // p = 0: i = dj
                        const int pr = dj >> 1, ln = dj & 1;
                        const v2f m = (c == 0) ? midA[k * 3 + pr] : midB[k * 3 + pr];
                        ve = ln ? m.y : m.x;
                    }
                    {   // p = 1: i = dj + 1
                        const int pr = (dj + 1) >> 1, ln = (dj + 1) & 1;
                        const v2f m = (c == 0) ? midA[k * 3 + pr] : midB[k * 3 + pr];
                        vo = ln ? m.y : m.x;
                    }
                    float cw = p ? vo : ve;
                    cw = fmaf(xra, smem[bufa * 196 + 2 + v + dj], cw);
                    cw = fmaf(xrb, smem[bufb * 196 + 2 + v + dj], cw);
                    red_s[v * 25 + k * 5 + dj] = cw;
                }
            }
            __syncthreads();
            float e0 = 0.f, e1 = 0.f, e190 = 0.f, e191 = 0.f;
            if (v < 25) {
                e0   = red_s[0 * 25 + v];
                e1   = red_s[1 * 25 + v];
                e190 = red_s[190 * 25 + v];
                e191 = red_s[191 * 25 + v];
            }
            __syncthreads();
            // tree reduce over columns: 192 -> 96 -> ... -> 3 (stride 25: conflict-free)
#pragma unroll
            for (int s = 96; s >= 3; s >>= 1) {
                for (int idx = v; idx < s * 25; idx += 192) {
                    const int vv = idx / 25, o = idx - vv * 25;
                    red_s[vv * 25 + o] += red_s[(vv + s) * 25 + o];
                }
                __syncthreads();
            }
            if (v < 25 && (c == 0 || bval)) {
                const int di = v / 5 - 2, dj = v - (v / 5) * 5 - 2;
                const int i2 = i1 + di;
                if (i2 >= 0 && i2 <= 2) {
                    const float S = red_s[0 * 25 + v] + red_s[1 * 25 + v] + red_s[2 * 25 + v];
                    const int c1 = (c == 0) ? c1a : c1b;
#pragma unroll
                    for (int j1 = 0; j1 < 3; ++j1) {
                        const int j2 = j1 + dj;
                        if (j2 < 0 || j2 > 2) continue;
                        const float W = S - ((j1 == 0) ? (e190 + e191)
                                          : (j1 == 1) ? (e0 + e191)
                                                      : (e0 + e1));
                        const int pp = c1 * 9 + i1 * 3 + j1;
                        const int qq = c2 * 9 + i2 * 3 + j2;
                        gp[pp * PP + qq] = (double)W;
                        if (c1 != c2) gp[qq * PP + pp] = (double)W;
                    }
                }
            }
            __syncthreads();   // red reused by next (i1,c)
        }
    }
}

// ---------------------------------------------------------------------------
// Kernel 2: per-group argmin (f64 d2, first-min tiebreak), bincount over both
// batches, stable top-3 (smallest index on count ties, matching lax.top_k).
// ---------------------------------------------------------------------------
__global__ __launch_bounds__(320) void topk_kernel(const double* __restrict__ gram,
                                                   float* __restrict__ pf,
                                                   int* __restrict__ pi)
{
    const int g = blockIdx.x;
    __shared__ double sdiag[2][PP];
    __shared__ int counts[PP];
    const int tid = threadIdx.x;
    if (tid < PP) counts[tid] = 0;
    if (tid < 2 * PP) {
        const int b = tid / PP, p = tid % PP;
        const double* gb = gram + (size_t)(b * 16 + g) * (PP * PP);
        sdiag[b][p] = gb[p * PP + p];
    }
    __syncthreads();
    if (tid < 2 * PP) {
        const int b = tid / PP, p = tid % PP;
        const double* row = gram + ((size_t)(b * 16 + g) * PP + p) * PP;
        const double sp = sdiag[b][p];
        double best = 1e300;
        int bi = 0;
        for (int q = 0; q < PP; ++q) {
            if (q == p) continue;
            const double d2 = sp + sdiag[b][q] - 2.0 * row[q];
            if (d2 < best) { best = d2; bi = q; }   // strict < : first occurrence
        }
        atomicAdd(&counts[bi], 1);
    }
    __syncthreads();
    if (tid == 0) {
        int sel[3], cv[3];
        for (int o = 0; o < 3; ++o) {
            int bc = -1, bp = 0;
            for (int p = 0; p < PP; ++p) {
                bool taken = false;
                for (int u = 0; u < o; ++u) if (sel[u] == p) taken = true;
                if (!taken && counts[p] > bc) { bc = counts[p]; bp = p; } // > keeps lowest idx
            }
            sel[o] = bp; cv[o] = bc;
        }
        const int tot = cv[0] + cv[1] + cv[2];
        for (int o = 0; o < 3; ++o) {
            pf[g * 4 + o] = (float)cv[o];
            pi[g * 4 + o] = sel[o];
        }
        pf[g * 4 + 3] = (float)tot;
    }
}

// ---------------------------------------------------------------------------
// Kernel 3: fused scale->floor->fold stencil. t1,t2 are plain f32 muls
// (== __fmul_rn == reference). Division via f64 reciprocal-multiply:
// bit-exact (total<=288 => exact quotients >=2^-34 rel from any f32 rounding
// midpoint, exact ties impossible, f64 error <=2^-52 -> identical rounding).
// Interior and edge in separate kernels (no divergent waves).
// ---------------------------------------------------------------------------
template <bool EDGE>
__device__ __forceinline__ void motif_quad(const float* __restrict__ x,
                                           const float* __restrict__ pf,
                                           const int* __restrict__ pi,
                                           float* __restrict__ out,
                                           int b, int ch, int h, int w0)
{
    const int g = ch >> 4;
    const size_t base = ((size_t)(b * NC + ch)) * (HH * WW);
    const float4 xv4 = *(const float4*)(x + base + (size_t)h * WW + w0);
    const float xs[4] = {xv4.x, xv4.y, xv4.z, xv4.w};
    float acc[4] = {0.f, 0.f, 0.f, 0.f};
    const float total = pf[g * 4 + 3];
    const double invd = 1.0 / (double)total;

#pragma unroll
    for (int o = 0; o < 3; ++o) {
        const int p = pi[g * 4 + o];
        const float cff = pf[g * 4 + o];
        const int co = p / 9;
        const int kk = p - co * 9;
        const int io = kk / 3, jo = kk - (kk / 3) * 3;
        const float* Rb = x + ((size_t)(b * NC + g * CG + co)) * (HH * WW);
#pragma unroll
        for (int i = 0; i < 3; ++i) {
            const int ho = h - i;
            bool rowok = true;
            int hr = ho + io;
            if (EDGE) {
                rowok = (ho >= 0) && (ho < HO);
                hr = hr < 0 ? 0 : (hr > HH - 1 ? HH - 1 : hr);
            }
            const float* row = Rb + (size_t)hr * WW;
            float rv[6];
#pragma unroll
            for (int u = 0; u < 6; ++u) {
                int col = w0 - 2 + jo + u;
                if (EDGE) col = col < 0 ? 0 : (col > WW - 1 ? WW - 1 : col);
                rv[u] = row[col];
            }
#pragma unroll
            for (int j = 0; j < 3; ++j)
#pragma unroll
            for (int q = 0; q < 4; ++q) {
                const float r2 = rv[q - j + 2];
                const float t1 = xs[q] * r2;                  // == __fmul_rn
                const float t2 = t1 * cff;                    // == __fmul_rn
                const float qf = (float)((double)t2 * invd);  // == __fdiv_rn(t2,total)
                const float vfl = floorf(qf);
                if (EDGE) {
                    const int wo = w0 + q - j;
                    const bool ok = rowok && (wo >= 0) && (wo < HO);
                    acc[q] += ok ? vfl : 0.f;
                } else {
                    acc[q] += vfl;
                }
            }
        }
    }
    float4 ov = make_float4(acc[0], acc[1], acc[2], acc[3]);
    *(float4*)(out + base + (size_t)h * WW + w0) = ov;
}

// interior: h in [2,189], w4 in [1,46] -> no clamps/masks anywhere.
__global__ __launch_bounds__(256) void out_interior(const float* __restrict__ x,
                                                    const float* __restrict__ pf,
                                                    const int* __restrict__ pi,
                                                    float* __restrict__ out)
{
    const int gid = blockIdx.x * 256 + threadIdx.x;
    const int w4i = gid % 46;
    int t = gid / 46;
    const int h = 2 + t % 188; t /= 188;
    const int ch = t & 255;
    const int b = t >> 8;
    motif_quad<false>(x, pf, pi, out, b, ch, h, (w4i + 1) * 4);
}

// edge: 568 quads per (b,ch): h in {0,1,190,191} x all 48 w4, plus
// h in [2,189] x w4 in {0,47}.
__global__ __launch_bounds__(256) void out_edge(const float* __restrict__ x,
                                                const float* __restrict__ pf,
                                                const int* __restrict__ pi,
                                                float* __restrict__ out)
{
    const int gid = blockIdx.x * 256 + threadIdx.x;
    const int e = gid % 568;
    int t = gid / 568;
    const int ch = t & 255;
    const int b = t >> 8;
    int h, w4;
    if (e < 192) {
        const int hs = e / 48;
        h = (hs < 2) ? hs : 188 + hs;         // 0,1,190,191
        w4 = e % 48;
    } else {
        const int e2 = e - 192;
        h = 2 + (e2 >> 1);
        w4 = (e2 & 1) ? 47 : 0;
    }
    motif_quad<true>(x, pf, pi, out, b, ch, h, w4 * 4);
}

// ---------------------------------------------------------------------------
extern "C" void kernel_launch(void* const* d_in, const int* in_sizes, int n_in,
                              void* d_out, int out_size, void* d_ws, size_t ws_size,
                              hipStream_t stream)
{
    const float* x = (const float*)d_in[0];
    float* out = (float*)d_out;

    double* gram = (double*)d_ws;
    const size_t gram_bytes = (size_t)32 * PP * PP * sizeof(double); // 5,308,416 B
    float* pf = (float*)((char*)d_ws + gram_bytes);
    int* pi = (int*)((char*)d_ws + gram_bytes + 256);

    gram_kernel<<<2304, 192, 0, stream>>>(x, gram);
    topk_kernel<<<16, 320, 0, stream>>>(gram, pf, pi);
    out_interior<<<17296, 256, 0, stream>>>(x, pf, pi, out);  // 2*256*188*46/256
    out_edge<<<1136, 256, 0, stream>>>(x, pf, pi, out);       // 2*256*568/256
}

// Round 13
// 416.685 us; speedup vs baseline: 1.1675x; 1.0097x over previous
//
#include <hip/hip_runtime.h>
#include <math.h>

// Problem constants
#define NB 2
#define NC 256
#define CG 16
#define HH 192
#define WW 192
#define HO 190
#define PP 144

typedef float v2f __attribute__((ext_vector_type(2)));

// LDS: 7348 floats = 29392 B.
// Band area: 36 rows x 196 (row r at r*196: [0..3]=pads always zero,
//   [4..195]=data, data col c at slot 4+c). Thread v's window = data cols
//   v-2..v+2 = slots v+2..v+6; b64 window reads use base bb=(v+2)&~1 (even ->
//   8B-aligned for ALL lanes), 6 floats bb..bb+5 = window positions i=0..5,
//   dj = i - p with p = v&1 (one garbage lane -> dummy accumulator lane).
// Epilogue: edge rows 0..11 (same layout), row 12 = permanent zero guard,
//   red[192][25] at 2548 (band rows >=13 alias red; bands done before use).
#define SMEM_FLOATS 7348

// ---------------------------------------------------------------------------
// Kernel 1: correlation-decomposed Gram. Bit-identical per-accumulator FMA
// values/order vs rounds 1-9/12.
// THIS ROUND: the staging loop (unchanged since r2!) had a RUNTIME trip count
// (full?9:3) -> not unrollable -> 9 serialized global->LDS round trips per
// band (9 x ~250-400cy on every wave's critical path between barriers,
// x7 bands ~ the whole compute loop). That is the invariant ~65% stall that
// survived pk-packing, ring pipelining, occupancy and split experiments.
// Fix = register-staged async prefetch (load-early/write-late):
//   - strength-reduced staging indices (ldst + it*784, gsrc + it*4*WW, all
//     compile-time immediates), #pragma unroll -> 9 independent loads;
//   - band k+1's loads issue right after band k's staging barrier and stay
//     in flight under band k's 30-step compute; at band k+1's top: barrier,
//     9 x ds_write_b128, barrier. Global latency leaves the critical path;
//   - band loop split into 6 compile-time full bands + explicit 8-step tail.
// Structure otherwise = r12: 192 thr, (192,2), dj-pair pk packing, b64
// window reads, 6-phase pipelined window ring, 6-deep global ring,
// XCD-clustered swizzle, direct f64 stores.
// ---------------------------------------------------------------------------
__global__ __launch_bounds__(192, 2) void gram_kernel(const float* __restrict__ x,
                                                      double* __restrict__ gram)
{
    __shared__ float smem[SMEM_FLOATS];
    float* const red_s = smem + 2548;

    const int v = threadIdx.x;                // column 0..191
    const int p = v & 1;                      // window parity: dj = i - p
    const int bb = (v + 2) & ~1;              // even b64 base slot
    const int vr = v / 48;                    // staging row sub-index 0..3
    const int vc4 = (v - vr * 48) * 4;        // staging col (floats)

    // XCD-clustered decode: bid%8 = intended XCD; half-group hg (36 blocks)
    // pinned to XCD hg%8. Bijective over 2304 blocks.
    const int bid = blockIdx.x;
    const int vx = bid & 7;
    const int tq = bid >> 3;                  // 0..287
    const int idxw = tq / 36;                 // 0..7
    const int rr0 = tq - idxw * 36;           // 0..35
    const int hg = idxw * 8 + vx;             // 0..63
    const int bg = hg >> 1;
    int r = rr0 + 36 * (hg & 1);              // 0..71
    int c2 = 0;
    while (r >= (c2 + 2) / 2) { r -= (c2 + 2) / 2; ++c2; }
    const int c1a = 2 * r;
    int c1b = 2 * r + 1;
    const bool bval = (c1b <= c2);
    if (!bval) c1b = c2;
    const int b = bg >> 4, g = bg & 15;

    const float* __restrict__ xa  = x + ((size_t)(b * NC + g * CG + c1a)) * (HH * WW);
    const float* __restrict__ xb  = x + ((size_t)(b * NC + g * CG + c1b)) * (HH * WW);
    const float* __restrict__ x2g = x + ((size_t)(b * NC + g * CG + c2 )) * (HH * WW);

    // zero pad slots [0..3] of rows 0..36 once; staging never writes pads.
    if (v < 148) smem[(v >> 2) * 196 + (v & 3)] = 0.f;

    // accumulators: lanes = window positions (2*pr, 2*pr+1); dj = pos - p.
    v2f midA[15], midB[15];                   // [k*3 + pr]
#pragma unroll
    for (int o = 0; o < 15; ++o) { midA[o] = (v2f){0.f, 0.f}; midB[o] = (v2f){0.f, 0.f}; }

    v2f win[6][3];                            // slot s: local row L (L%6==s), 3 pairs
    float ca[6], cb[6];                       // ca[(u-2)%6] holds xa row u
#pragma unroll
    for (int k = 0; k < 6; ++k) {             // rows 2..7
        ca[k] = xa[(size_t)(2 + k) * WW + v];
        cb[k] = xb[(size_t)(2 + k) * WW + v];
    }

    const float* pa = xa + (size_t)8 * WW + v;   // refill base (row ubase+6)
    const float* pb = xb + (size_t)8 * WW + v;
    int lds_off;                              // float idx of WPF row b64 base

    // staging: fixed per-thread source (row vr, col vc4) and LDS slot;
    // group it covers local rows it*4+vr (36 rows/band; row 35 is a harmless
    // in-bounds overwrite, never read).
    const float* gsrc = x2g + (size_t)vr * WW + vc4;
    float* const ldst = &smem[vr * 196 + 4 + vc4];

    float4 tmp[9];
#pragma unroll
    for (int it = 0; it < 9; ++it)            // band 0 rows (row0 = 0)
        tmp[it] = *(const float4*)(gsrc + (size_t)(it * 4) * WW);

// One u-step. P = phase = LS%6 (compile-time). Consumes ca/cb[P] (row u) and
// win slots (P+kk)%6 (local rows LS..LS+4, loaded >=1 step earlier).
//   WPF: window row local LS+5 -> slot (P+5)%6: 3 x ds_read_b64;
//   GPF: ca/cb[P] <- rows at pa/pb[P*WW] (consumed 6 steps later).
#define USTEP6(P, WPF, GPF)                                                   \
    {                                                                         \
        const float a1 = ca[(P)];                                             \
        const float b1 = cb[(P)];                                             \
        if (GPF) { ca[(P)] = pa[(P) * WW]; cb[(P)] = pb[(P) * WW]; }          \
        if (WPF) {                                                            \
            _Pragma("unroll")                                                 \
            for (int pr = 0; pr < 3; ++pr)                                    \
                win[((P) + 5) % 6][pr] = *(const v2f*)(&smem[lds_off + 2 * pr]); \
        }                                                                     \
        lds_off += 196;                                                       \
        const v2f a2 = (v2f){a1, a1};                                         \
        const v2f b2 = (v2f){b1, b1};                                         \
        _Pragma("unroll")                                                     \
        for (int kk = 0; kk < 5; ++kk) {                                      \
            _Pragma("unroll")                                                 \
            for (int pr = 0; pr < 3; ++pr) {                                  \
                const v2f wv = win[((P) + kk) % 6][pr];                       \
                midA[kk * 3 + pr] = __builtin_elementwise_fma(a2, wv, midA[kk * 3 + pr]); \
                midB[kk * 3 + pr] = __builtin_elementwise_fma(b2, wv, midB[kk * 3 + pr]); \
            }                                                                 \
        }                                                                     \
    }

    // 6 full bands x 30 steps (u=2..181) + 8-step tail (u=182..189).
    // Step LS=29's WPF loads local 34 = next band's local 4 -> bands chain;
    // only band 0 has a prologue.
    for (int band = 0; band < 6; ++band) {
        __syncthreads();                      // prev band's readers done
#pragma unroll
        for (int it = 0; it < 9; ++it)        // write-late: 9 x ds_write_b128
            *(float4*)(ldst + it * 784) = tmp[it];
        __syncthreads();                      // staging visible

        if (band == 0) {
            // only prologue of the kernel: locals 0..4 -> slots 0..4
#pragma unroll
            for (int k = 0; k < 5; ++k)
#pragma unroll
            for (int pr = 0; pr < 3; ++pr)
                win[k][pr] = *(const v2f*)(&smem[k * 196 + bb + 2 * pr]);
        }

        // load-early: next band's rows, in flight under this band's compute
        if (band < 5) {
            const float* gn = gsrc + (size_t)((band + 1) * 30) * WW;
#pragma unroll
            for (int it = 0; it < 9; ++it)
                tmp[it] = *(const float4*)(gn + (size_t)(it * 4) * WW);
        } else {
            // tail rows 180..191 (3 groups)
#pragma unroll
            for (int it = 0; it < 3; ++it)
                tmp[it] = *(const float4*)(gsrc + (size_t)(180 + it * 4) * WW);
        }

        lds_off = 5 * 196 + bb;               // local row 5, this band
        for (int it = 0; it < 5; ++it) {      // rolled: small hot body
            USTEP6(0, 1, 1) USTEP6(1, 1, 1) USTEP6(2, 1, 1)
            USTEP6(3, 1, 1) USTEP6(4, 1, 1) USTEP6(5, 1, 1)
            pa += 6 * WW; pb += 6 * WW;       // next group's refill base
        }
    }
    // tail band: stage 12 rows (locals 0..11 = abs 180..191), 8 steps
    __syncthreads();
#pragma unroll
    for (int it = 0; it < 3; ++it)
        *(float4*)(ldst + it * 784) = tmp[it];
    __syncthreads();
    lds_off = 5 * 196 + bb;
    // steps 0..5 (u=182..187); GPF only P<=1 (rows 188,189: pa at row 188)
    USTEP6(0, 1, 1) USTEP6(1, 1, 1) USTEP6(2, 1, 0)
    USTEP6(3, 1, 0) USTEP6(4, 1, 0) USTEP6(5, 1, 0)
    // steps 6,7 (u=188,189): phases 0,1; WPF for LS=6 (local 11)
    USTEP6(0, 1, 0) USTEP6(1, 0, 0)
#undef USTEP6

    // stage edge buffer: buf i<6 -> abs row i-2 (OOB zero), i>=6 -> 188+(i-6).
    // Row 12 = zero guard; red_s at 2548.
    __syncthreads();
    for (int i = 0; i < 12; ++i) {
        const int ar = (i < 6) ? (i - 2) : (188 + i - 6);
        const float val = (ar >= 0 && ar <= 191) ? x2g[(size_t)ar * WW + v] : 0.f;
        smem[i * 196 + 4 + v] = val;
    }
    __syncthreads();

    double* const gp = gram + (size_t)bg * (PP * PP);

#pragma unroll
    for (int i1 = 0; i1 < 3; ++i1) {
        const int ra = (i1 == 0) ? 0 : ((i1 == 1) ? 1 : 190);
        const int rb = (i1 == 0) ? 1 : ((i1 == 1) ? 190 : 191);
#pragma unroll
        for (int c = 0; c < 2; ++c) {
            const float* __restrict__ xc = (c == 0) ? xa : xb;
            const float xra = xc[(size_t)ra * WW + v];
            const float xrb = xc[(size_t)rb * WW + v];
#pragma unroll
            for (int k = 0; k < 5; ++k) {
                const int bufa = (ra < 2) ? (ra + k) : (ra + k - 184);
                const int bufb = (rb < 2) ? (rb + k) : (rb + k - 184);
#pragma unroll
                for (int dj = 0; dj < 5; ++dj) {
                    // mid value for (c,k,dj): window position i = dj + p.
                    // Compile-time register indices; runtime select on p.
                    float ve, vo;
                    {   // p = 0: i = dj
                        const int pr = dj >> 1, ln = dj & 1;
                        const v2f m = (c == 0) ? midA[k * 3 + pr] : midB[k * 3 + pr];
                        ve = ln ? m.y : m.x;
                    }
                    {   // p = 1: i = dj + 1
                        const int pr = (dj + 1) >> 1, ln = (dj + 1) & 1;
                        const v2f m = (c == 0) ? midA[k * 3 + pr] : midB[k * 3 + pr];
                        vo = ln ? m.y : m.x;
                    }
                    float cw = p ? vo : ve;
                    cw = fmaf(xra, smem[bufa * 196 + 2 + v + dj], cw);
                    cw = fmaf(xrb, smem[bufb * 196 + 2 + v + dj], cw);
                    red_s[v * 25 + k * 5 + dj] = cw;
                }
            }
            __syncthreads();
            float e0 = 0.f, e1 = 0.f, e190 = 0.f, e191 = 0.f;
            if (v < 25) {
                e0   = red_s[0 * 25 + v];
                e1   = red_s[1 * 25 + v];
                e190 = red_s[190 * 25 + v];
                e191 = red_s[191 * 25 + v];
            }
            __syncthreads();
            // tree reduce over columns: 192 -> 96 -> ... -> 3 (stride 25: conflict-free)
#pragma unroll
            for (int s = 96; s >= 3; s >>= 1) {
                for (int idx = v; idx < s * 25; idx += 192) {
                    const int vv = idx / 25, o = idx - vv * 25;
                    red_s[vv * 25 + o] += red_s[(vv + s) * 25 + o];
                }
                __syncthreads();
            }
            if (v < 25 && (c == 0 || bval)) {
                const int di = v / 5 - 2, dj = v - (v / 5) * 5 - 2;
                const int i2 = i1 + di;
                if (i2 >= 0 && i2 <= 2) {
                    const float S = red_s[0 * 25 + v] + red_s[1 * 25 + v] + red_s[2 * 25 + v];
                    const int c1 = (c == 0) ? c1a : c1b;
#pragma unroll
                    for (int j1 = 0; j1 < 3; ++j1) {
                        const int j2 = j1 + dj;
                        if (j2 < 0 || j2 > 2) continue;
                        const float W = S - ((j1 == 0) ? (e190 + e191)
                                          : (j1 == 1) ? (e0 + e191)
                                                      : (e0 + e1));
                        const int pp = c1 * 9 + i1 * 3 + j1;
                        const int qq = c2 * 9 + i2 * 3 + j2;
                        gp[pp * PP + qq] = (double)W;
                        if (c1 != c2) gp[qq * PP + pp] = (double)W;
                    }
                }
            }
            __syncthreads();   // red reused by next (i1,c)
        }
    }
}

// ---------------------------------------------------------------------------
// Kernel 2: per-group argmin (f64 d2, first-min tiebreak), bincount over both
// batches, stable top-3 (smallest index on count ties, matching lax.top_k).
// ---------------------------------------------------------------------------
__global__ __launch_bounds__(320) void topk_kernel(const double* __restrict__ gram,
                                                   float* __restrict__ pf,
                                                   int* __restrict__ pi)
{
    const int g = blockIdx.x;
    __shared__ double sdiag[2][PP];
    __shared__ int counts[PP];
    const int tid = threadIdx.x;
    if (tid < PP) counts[tid] = 0;
    if (tid < 2 * PP) {
        const int b = tid / PP, p = tid % PP;
        const double* gb = gram + (size_t)(b * 16 + g) * (PP * PP);
        sdiag[b][p] = gb[p * PP + p];
    }
    __syncthreads();
    if (tid < 2 * PP) {
        const int b = tid / PP, p = tid % PP;
        const double* row = gram + ((size_t)(b * 16 + g) * PP + p) * PP;
        const double sp = sdiag[b][p];
        double best = 1e300;
        int bi = 0;
        for (int q = 0; q < PP; ++q) {
            if (q == p) continue;
            const double d2 = sp + sdiag[b][q] - 2.0 * row[q];
            if (d2 < best) { best = d2; bi = q; }   // strict < : first occurrence
        }
        atomicAdd(&counts[bi], 1);
    }
    __syncthreads();
    if (tid == 0) {
        int sel[3], cv[3];
        for (int o = 0; o < 3; ++o) {
            int bc = -1, bp = 0;
            for (int p = 0; p < PP; ++p) {
                bool taken = false;
                for (int u = 0; u < o; ++u) if (sel[u] == p) taken = true;
                if (!taken && counts[p] > bc) { bc = counts[p]; bp = p; } // > keeps lowest idx
            }
            sel[o] = bp; cv[o] = bc;
        }
        const int tot = cv[0] + cv[1] + cv[2];
        for (int o = 0; o < 3; ++o) {
            pf[g * 4 + o] = (float)cv[o];
            pi[g * 4 + o] = sel[o];
        }
        pf[g * 4 + 3] = (float)tot;
    }
}

// ---------------------------------------------------------------------------
// Kernel 3: fused scale->floor->fold stencil. t1,t2 are plain f32 muls
// (== __fmul_rn == reference). Division via f64 reciprocal-multiply:
// bit-exact (total<=288 => exact quotients >=2^-34 rel from any f32 rounding
// midpoint, exact ties impossible, f64 error <=2^-52 -> identical rounding).
// Interior and edge in separate kernels (no divergent waves).
// ---------------------------------------------------------------------------
template <bool EDGE>
__device__ __forceinline__ void motif_quad(const float* __restrict__ x,
                                           const float* __restrict__ pf,
                                           const int* __restrict__ pi,
                                           float* __restrict__ out,
                                           int b, int ch, int h, int w0)
{
    const int g = ch >> 4;
    const size_t base = ((size_t)(b * NC + ch)) * (HH * WW);
    const float4 xv4 = *(const float4*)(x + base + (size_t)h * WW + w0);
    const float xs[4] = {xv4.x, xv4.y, xv4.z, xv4.w};
    float acc[4] = {0.f, 0.f, 0.f, 0.f};
    const float total = pf[g * 4 + 3];
    const double invd = 1.0 / (double)total;

#pragma unroll
    for (int o = 0; o < 3; ++o) {
        const int p = pi[g * 4 + o];
        const float cff = pf[g * 4 + o];
        const int co = p / 9;
        const int kk = p - co * 9;
        const int io = kk / 3, jo = kk - (kk / 3) * 3;
        const float* Rb = x + ((size_t)(b * NC + g * CG + co)) * (HH * WW);
#pragma unroll
        for (int i = 0; i < 3; ++i) {
            const int ho = h - i;
            bool rowok = true;
            int hr = ho + io;
            if (EDGE) {
                rowok = (ho >= 0) && (ho < HO);
                hr = hr < 0 ? 0 : (hr > HH - 1 ? HH - 1 : hr);
            }
            const float* row = Rb + (size_t)hr * WW;
            float rv[6];
#pragma unroll
            for (int u = 0; u < 6; ++u) {
                int col = w0 - 2 + jo + u;
                if (EDGE) col = col < 0 ? 0 : (col > WW - 1 ? WW - 1 : col);
                rv[u] = row[col];
            }
#pragma unroll
            for (int j = 0; j < 3; ++j)
#pragma unroll
            for (int q = 0; q < 4; ++q) {
                const float r2 = rv[q - j + 2];
                const float t1 = xs[q] * r2;                  // == __fmul_rn
                const float t2 = t1 * cff;                    // == __fmul_rn
                const float qf = (float)((double)t2 * invd);  // == __fdiv_rn(t2,total)
                const float vfl = floorf(qf);
                if (EDGE) {
                    const int wo = w0 + q - j;
                    const bool ok = rowok && (wo >= 0) && (wo < HO);
                    acc[q] += ok ? vfl : 0.f;
                } else {
                    acc[q] += vfl;
                }
            }
        }
    }
    float4 ov = make_float4(acc[0], acc[1], acc[2], acc[3]);
    *(float4*)(out + base + (size_t)h * WW + w0) = ov;
}

// interior: h in [2,189], w4 in [1,46] -> no clamps/masks anywhere.
__global__ __launch_bounds__(256) void out_interior(const float* __restrict__ x,
                                                    const float* __restrict__ pf,
                                                    const int* __restrict__ pi,
                                                    float* __restrict__ out)
{
    const int gid = blockIdx.x * 256 + threadIdx.x;
    const int w4i = gid % 46;
    int t = gid / 46;
    const int h = 2 + t % 188; t /= 188;
    const int ch = t & 255;
    const int b = t >> 8;
    motif_quad<false>(x, pf, pi, out, b, ch, h, (w4i + 1) * 4);
}

// edge: 568 quads per (b,ch): h in {0,1,190,191} x all 48 w4, plus
// h in [2,189] x w4 in {0,47}.
__global__ __launch_bounds__(256) void out_edge(const float* __restrict__ x,
                                                const float* __restrict__ pf,
                                                const int* __restrict__ pi,
                                                float* __restrict__ out)
{
    const int gid = blockIdx.x * 256 + threadIdx.x;
    const int e = gid % 568;
    int t = gid / 568;
    const int ch = t & 255;
    const int b = t >> 8;
    int h, w4;
    if (e < 192) {
        const int hs = e / 48;
        h = (hs < 2) ? hs : 188 + hs;         // 0,1,190,191
        w4 = e % 48;
    } else {
        const int e2 = e - 192;
        h = 2 + (e2 >> 1);
        w4 = (e2 & 1) ? 47 : 0;
    }
    motif_quad<true>(x, pf, pi, out, b, ch, h, w4 * 4);
}

// ---------------------------------------------------------------------------
extern "C" void kernel_launch(void* const* d_in, const int* in_sizes, int n_in,
                              void* d_out, int out_size, void* d_ws, size_t ws_size,
                              hipStream_t stream)
{
    const float* x = (const float*)d_in[0];
    float* out = (float*)d_out;

    double* gram = (double*)d_ws;
    const size_t gram_bytes = (size_t)32 * PP * PP * sizeof(double); // 5,308,416 B
    float* pf = (float*)((char*)d_ws + gram_bytes);
    int* pi = (int*)((char*)d_ws + gram_bytes + 256);

    gram_kernel<<<2304, 192, 0, stream>>>(x, gram);
    topk_kernel<<<16, 320, 0, stream>>>(gram, pf, pi);
    out_interior<<<17296, 256, 0, stream>>>(x, pf, pi, out);  // 2*256*188*46/256
    out_edge<<<1136, 256, 0, stream>>>(x, pf, pi, out);       // 2*256*568/256
}

// Round 14
// 364.075 us; speedup vs baseline: 1.3363x; 1.1445x over previous
//
#include <hip/hip_runtime.h>
#include <math.h>

// Problem constants
#define NB 2
#define NC 256
#define CG 16
#define HH 192
#define WW 192
#define HO 190
#define PP 144

typedef float v2f __attribute__((ext_vector_type(2)));

// LDS: 7348 floats = 29392 B.
// Band area: 35 rows x 49 float4-slots (196 floats/row: slots [0..3]=pads,
//   [4..195]=data, data col c at 4+c). Staged LINEARLY by global_load_lds
//   (lane*16B); pad-slot lanes load a harmless dup and pads are re-zeroed
//   after the drain barrier (guide m173: pre-swizzle the per-lane GLOBAL
//   address, keep LDS linear). Thread v's window = data cols v-2..v+2 =
//   slots v+2..v+6; b64 reads use even base bb=(v+2)&~1 (8B-aligned),
//   6 floats = window positions i=0..5, dj = i - (v&1).
// Epilogue: edge rows 0..11 (same layout), row 12 = permanent zero guard,
//   red[192][25] at 2548 (aliases band rows >=13; bands done before use).
#define SMEM_FLOATS 7348

#define GLD16(GP, LP)                                                         \
    __builtin_amdgcn_global_load_lds(                                         \
        (const __attribute__((address_space(1))) void*)(GP),                  \
        (__attribute__((address_space(3))) void*)(LP), 16, 0, 0)

// ---------------------------------------------------------------------------
// Kernel 1: correlation-decomposed Gram. Bit-identical per-accumulator FMA
// values/order vs rounds 1-9/12.
// THIS ROUND: staging via __builtin_amdgcn_global_load_lds (direct
// global->LDS, no VGPR round trip). r13 proved the staging-serialization
// theory (rolled loop = 9 serialized ~400cy round trips/band) but its
// register prefetch spilled (tmp[9]=36 VGPR live across 30 steps -> VGPR 84,
// 360MB scratch). global_load_lds: 9 independent loads in flight, one
// vmcnt(0) drain at the barrier, ZERO register cost. Per-lane global source
// computed from linear slot decomposition (slot/49); pad lanes redirected,
// pads re-zeroed (+1 barrier/band). Compute = r12: 192 thr, (192,2),
// dj-pair pk packing, b64 window reads, 6-phase pipelined window ring,
// 6-deep global ring, XCD-clustered swizzle, direct f64 stores.
// ---------------------------------------------------------------------------
__global__ __launch_bounds__(192, 2) void gram_kernel(const float* __restrict__ x,
                                                      double* __restrict__ gram)
{
    __shared__ __align__(16) float smem[SMEM_FLOATS];
    float* const red_s = smem + 2548;

    const int v = threadIdx.x;                // column 0..191
    const int p = v & 1;                      // window parity: dj = i - p
    const int bb = (v + 2) & ~1;              // even b64 base slot

    // XCD-clustered decode: bid%8 = intended XCD; half-group hg (36 blocks)
    // pinned to XCD hg%8. Bijective over 2304 blocks.
    const int bid = blockIdx.x;
    const int vx = bid & 7;
    const int tq = bid >> 3;                  // 0..287
    const int idxw = tq / 36;                 // 0..7
    const int rr0 = tq - idxw * 36;           // 0..35
    const int hg = idxw * 8 + vx;             // 0..63
    const int bg = hg >> 1;
    int r = rr0 + 36 * (hg & 1);              // 0..71
    int c2 = 0;
    while (r >= (c2 + 2) / 2) { r -= (c2 + 2) / 2; ++c2; }
    const int c1a = 2 * r;
    int c1b = 2 * r + 1;
    const bool bval = (c1b <= c2);
    if (!bval) c1b = c2;
    const int b = bg >> 4, g = bg & 15;

    const float* __restrict__ xa  = x + ((size_t)(b * NC + g * CG + c1a)) * (HH * WW);
    const float* __restrict__ xb  = x + ((size_t)(b * NC + g * CG + c1b)) * (HH * WW);
    const float* __restrict__ x2g = x + ((size_t)(b * NC + g * CG + c2 )) * (HH * WW);

    // accumulators: lanes = window positions (2*pr, 2*pr+1); dj = pos - p.
    v2f midA[15], midB[15];                   // [k*3 + pr]
#pragma unroll
    for (int o = 0; o < 15; ++o) { midA[o] = (v2f){0.f, 0.f}; midB[o] = (v2f){0.f, 0.f}; }

    v2f win[6][3];                            // slot s: local row L (L%6==s), 3 pairs
    float ca[6], cb[6];                       // ca[(u-2)%6] holds xa row u
#pragma unroll
    for (int k = 0; k < 6; ++k) {             // rows 2..7
        ca[k] = xa[(size_t)(2 + k) * WW + v];
        cb[k] = xb[(size_t)(2 + k) * WW + v];
    }

    const float* pa = xa + (size_t)8 * WW + v;   // refill base (row ubase+6)
    const float* pb = xb + (size_t)8 * WW + v;
    int lds_off;                              // float idx of WPF row b64 base

// One u-step. P = phase = LS%6 (compile-time). Consumes ca/cb[P] (row u) and
// win slots (P+kk)%6 (local rows LS..LS+4, loaded >=1 step earlier).
//   WPF: window row local LS+5 -> slot (P+5)%6: 3 x ds_read_b64;
//   GPF: ca/cb[P] <- rows at pa/pb[P*WW] (consumed 6 steps later).
#define USTEP6(P, WPF, GPF)                                                   \
    {                                                                         \
        const float a1 = ca[(P)];                                             \
        const float b1 = cb[(P)];                                             \
        if (GPF) { ca[(P)] = pa[(P) * WW]; cb[(P)] = pb[(P) * WW]; }          \
        if (WPF) {                                                            \
            _Pragma("unroll")                                                 \
            for (int pr = 0; pr < 3; ++pr)                                    \
                win[((P) + 5) % 6][pr] = *(const v2f*)(&smem[lds_off + 2 * pr]); \
        }                                                                     \
        lds_off += 196;                                                       \
        const v2f a2 = (v2f){a1, a1};                                         \
        const v2f b2 = (v2f){b1, b1};                                         \
        _Pragma("unroll")                                                     \
        for (int kk = 0; kk < 5; ++kk) {                                      \
            _Pragma("unroll")                                                 \
            for (int pr = 0; pr < 3; ++pr) {                                  \
                const v2f wv = win[((P) + kk) % 6][pr];                       \
                midA[kk * 3 + pr] = __builtin_elementwise_fma(a2, wv, midA[kk * 3 + pr]); \
                midB[kk * 3 + pr] = __builtin_elementwise_fma(b2, wv, midB[kk * 3 + pr]); \
            }                                                                 \
        }                                                                     \
    }

// Stage NSLOTS float4 slots (rows [ROW0, ROW0+NROWS)) linearly via
// global_load_lds; then drain + re-zero pads (rows 0..35) + barrier.
// slot = rr*192+v; row = slot/49; s49 = slot%49; s49==0 is a pad slot ->
// load dup of col 0 (overwritten by the re-zero).
#define STAGE(ROW0, NROUND, LASTN)                                            \
    __syncthreads();                                                          \
    _Pragma("unroll")                                                         \
    for (int rr2 = 0; rr2 < (NROUND); ++rr2) {                                \
        if (rr2 < (NROUND) - 1 || v < (LASTN)) {                              \
            const int slot = rr2 * 192 + v;                                   \
            const int row = slot / 49;                                        \
            const int s49 = slot - row * 49;                                  \
            const int col = (s49 == 0) ? 0 : (s49 - 1) * 4;                   \
            const float* gp2 = x2g + (size_t)((ROW0) + row) * WW + col;       \
            float* lp = smem + (rr2 * 192 + (v & ~63)) * 4;                   \
            GLD16(gp2, lp);                                                   \
        }                                                                     \
    }                                                                         \
    __syncthreads();                                                          \
    if (v < 144) smem[(v >> 2) * 196 + (v & 3)] = 0.f;                        \
    __syncthreads();

    // 6 full bands x 30 steps (u=2..181, stage 35 rows = 1715 slots: 9
    // rounds, last 179) + 8-step tail (u=182..189, stage 12 rows = 588
    // slots: 4 rounds, last 12). Step LS=29's WPF loads local 34 = next
    // band's local 4 -> bands chain in registers; only band 0 has a prologue.
    for (int band = 0; band < 6; ++band) {
        const int row0 = band * 30;
        STAGE(row0, 9, 179)

        if (band == 0) {
            // only prologue of the kernel: locals 0..4 -> slots 0..4
#pragma unroll
            for (int k = 0; k < 5; ++k)
#pragma unroll
            for (int pr = 0; pr < 3; ++pr)
                win[k][pr] = *(const v2f*)(&smem[k * 196 + bb + 2 * pr]);
        }

        lds_off = 5 * 196 + bb;               // local row 5, this band
        for (int it = 0; it < 5; ++it) {      // rolled: small hot body
            USTEP6(0, 1, 1) USTEP6(1, 1, 1) USTEP6(2, 1, 1)
            USTEP6(3, 1, 1) USTEP6(4, 1, 1) USTEP6(5, 1, 1)
            pa += 6 * WW; pb += 6 * WW;       // next group's refill base
        }
    }
    // tail band: rows 180..191 at locals 0..11
    STAGE(180, 4, 12)
    lds_off = 5 * 196 + bb;
    // steps 0..5 (u=182..187); GPF only P<=1 (rows 188,189: pa at row 188)
    USTEP6(0, 1, 1) USTEP6(1, 1, 1) USTEP6(2, 1, 0)
    USTEP6(3, 1, 0) USTEP6(4, 1, 0) USTEP6(5, 1, 0)
    // steps 6,7 (u=188,189): phases 0,1; WPF for LS=6 (local 11)
    USTEP6(0, 1, 0) USTEP6(1, 0, 0)
#undef USTEP6
#undef STAGE

    // stage edge buffer: buf i<6 -> abs row i-2 (OOB zero), i>=6 -> 188+(i-6).
    // Pads of rows 0..12 still zero from the tail re-zero. Row 12 = zero
    // guard; red_s at 2548.
    __syncthreads();
    for (int i = 0; i < 12; ++i) {
        const int ar = (i < 6) ? (i - 2) : (188 + i - 6);
        const float val = (ar >= 0 && ar <= 191) ? x2g[(size_t)ar * WW + v] : 0.f;
        smem[i * 196 + 4 + v] = val;
    }
    __syncthreads();

    double* const gp = gram + (size_t)bg * (PP * PP);

#pragma unroll
    for (int i1 = 0; i1 < 3; ++i1) {
        const int ra = (i1 == 0) ? 0 : ((i1 == 1) ? 1 : 190);
        const int rb = (i1 == 0) ? 1 : ((i1 == 1) ? 190 : 191);
#pragma unroll
        for (int c = 0; c < 2; ++c) {
            const float* __restrict__ xc = (c == 0) ? xa : xb;
            const float xra = xc[(size_t)ra * WW + v];
            const float xrb = xc[(size_t)rb * WW + v];
#pragma unroll
            for (int k = 0; k < 5; ++k) {
                const int bufa = (ra < 2) ? (ra + k) : (ra + k - 184);
                const int bufb = (rb < 2) ? (rb + k) : (rb + k - 184);
#pragma unroll
                for (int dj = 0; dj < 5; ++dj) {
                    // mid value for (c,k,dj): window position i = dj + p.
                    // Compile-time register indices; runtime select on p.
                    float ve, vo;
                    {   // p = 0: i = dj
                        const int pr = dj >> 1, ln = dj & 1;
                        const v2f m = (c == 0) ? midA[k * 3 + pr] : midB[k * 3 + pr];
                        ve = ln ? m.y : m.x;
                    }
                    {   // p = 1: i = dj + 1
                        const int pr = (dj + 1) >> 1, ln = (dj + 1) & 1;
                        const v2f m = (c == 0) ? midA[k * 3 + pr] : midB[k * 3 + pr];
                        vo = ln ? m.y : m.x;
                    }
                    float cw = p ? vo : ve;
                    cw = fmaf(xra, smem[bufa * 196 + 2 + v + dj], cw);
                    cw = fmaf(xrb, smem[bufb * 196 + 2 + v + dj], cw);
                    red_s[v * 25 + k * 5 + dj] = cw;
                }
            }
            __syncthreads();
            float e0 = 0.f, e1 = 0.f, e190 = 0.f, e191 = 0.f;
            if (v < 25) {
                e0   = red_s[0 * 25 + v];
                e1   = red_s[1 * 25 + v];
                e190 = red_s[190 * 25 + v];
                e191 = red_s[191 * 25 + v];
            }
            __syncthreads();
            // tree reduce over columns: 192 -> 96 -> ... -> 3 (stride 25: conflict-free)
#pragma unroll
            for (int s = 96; s >= 3; s >>= 1) {
                for (int idx = v; idx < s * 25; idx += 192) {
                    const int vv = idx / 25, o = idx - vv * 25;
                    red_s[vv * 25 + o] += red_s[(vv + s) * 25 + o];
                }
                __syncthreads();
            }
            if (v < 25 && (c == 0 || bval)) {
                const int di = v / 5 - 2, dj = v - (v / 5) * 5 - 2;
                const int i2 = i1 + di;
                if (i2 >= 0 && i2 <= 2) {
                    const float S = red_s[0 * 25 + v] + red_s[1 * 25 + v] + red_s[2 * 25 + v];
                    const int c1 = (c == 0) ? c1a : c1b;
#pragma unroll
                    for (int j1 = 0; j1 < 3; ++j1) {
                        const int j2 = j1 + dj;
                        if (j2 < 0 || j2 > 2) continue;
                        const float W = S - ((j1 == 0) ? (e190 + e191)
                                          : (j1 == 1) ? (e0 + e191)
                                                      : (e0 + e1));
                        const int pp = c1 * 9 + i1 * 3 + j1;
                        const int qq = c2 * 9 + i2 * 3 + j2;
                        gp[pp * PP + qq] = (double)W;
                        if (c1 != c2) gp[qq * PP + pp] = (double)W;
                    }
                }
            }
            __syncthreads();   // red reused by next (i1,c)
        }
    }
}

// ---------------------------------------------------------------------------
// Kernel 2: per-group argmin (f64 d2, first-min tiebreak), bincount over both
// batches, stable top-3 (smallest index on count ties, matching lax.top_k).
// ---------------------------------------------------------------------------
__global__ __launch_bounds__(320) void topk_kernel(const double* __restrict__ gram,
                                                   float* __restrict__ pf,
                                                   int* __restrict__ pi)
{
    const int g = blockIdx.x;
    __shared__ double sdiag[2][PP];
    __shared__ int counts[PP];
    const int tid = threadIdx.x;
    if (tid < PP) counts[tid] = 0;
    if (tid < 2 * PP) {
        const int b = tid / PP, p = tid % PP;
        const double* gb = gram + (size_t)(b * 16 + g) * (PP * PP);
        sdiag[b][p] = gb[p * PP + p];
    }
    __syncthreads();
    if (tid < 2 * PP) {
        const int b = tid / PP, p = tid % PP;
        const double* row = gram + ((size_t)(b * 16 + g) * PP + p) * PP;
        const double sp = sdiag[b][p];
        double best = 1e300;
        int bi = 0;
        for (int q = 0; q < PP; ++q) {
            if (q == p) continue;
            const double d2 = sp + sdiag[b][q] - 2.0 * row[q];
            if (d2 < best) { best = d2; bi = q; }   // strict < : first occurrence
        }
        atomicAdd(&counts[bi], 1);
    }
    __syncthreads();
    if (tid == 0) {
        int sel[3], cv[3];
        for (int o = 0; o < 3; ++o) {
            int bc = -1, bp = 0;
            for (int p = 0; p < PP; ++p) {
                bool taken = false;
                for (int u = 0; u < o; ++u) if (sel[u] == p) taken = true;
                if (!taken && counts[p] > bc) { bc = counts[p]; bp = p; } // > keeps lowest idx
            }
            sel[o] = bp; cv[o] = bc;
        }
        const int tot = cv[0] + cv[1] + cv[2];
        for (int o = 0; o < 3; ++o) {
            pf[g * 4 + o] = (float)cv[o];
            pi[g * 4 + o] = sel[o];
        }
        pf[g * 4 + 3] = (float)tot;
    }
}

// ---------------------------------------------------------------------------
// Kernel 3: fused scale->floor->fold stencil. t1,t2 are plain f32 muls
// (== __fmul_rn == reference). Division via f64 reciprocal-multiply:
// bit-exact (total<=288 => exact quotients >=2^-34 rel from any f32 rounding
// midpoint, exact ties impossible, f64 error <=2^-52 -> identical rounding).
// Interior and edge in separate kernels (no divergent waves).
// ---------------------------------------------------------------------------
template <bool EDGE>
__device__ __forceinline__ void motif_quad(const float* __restrict__ x,
                                           const float* __restrict__ pf,
                                           const int* __restrict__ pi,
                                           float* __restrict__ out,
                                           int b, int ch, int h, int w0)
{
    const int g = ch >> 4;
    const size_t base = ((size_t)(b * NC + ch)) * (HH * WW);
    const float4 xv4 = *(const float4*)(x + base + (size_t)h * WW + w0);
    const float xs[4] = {xv4.x, xv4.y, xv4.z, xv4.w};
    float acc[4] = {0.f, 0.f, 0.f, 0.f};
    const float total = pf[g * 4 + 3];
    const double invd = 1.0 / (double)total;

#pragma unroll
    for (int o = 0; o < 3; ++o) {
        const int p = pi[g * 4 + o];
        const float cff = pf[g * 4 + o];
        const int co = p / 9;
        const int kk = p - co * 9;
        const int io = kk / 3, jo = kk - (kk / 3) * 3;
        const float* Rb = x + ((size_t)(b * NC + g * CG + co)) * (HH * WW);
#pragma unroll
        for (int i = 0; i < 3; ++i) {
            const int ho = h - i;
            bool rowok = true;
            int hr = ho + io;
            if (EDGE) {
                rowok = (ho >= 0) && (ho < HO);
                hr = hr < 0 ? 0 : (hr > HH - 1 ? HH - 1 : hr);
            }
            const float* row = Rb + (size_t)hr * WW;
            float rv[6];
#pragma unroll
            for (int u = 0; u < 6; ++u) {
                int col = w0 - 2 + jo + u;
                if (EDGE) col = col < 0 ? 0 : (col > WW - 1 ? WW - 1 : col);
                rv[u] = row[col];
            }
#pragma unroll
            for (int j = 0; j < 3; ++j)
#pragma unroll
            for (int q = 0; q < 4; ++q) {
                const float r2 = rv[q - j + 2];
                const float t1 = xs[q] * r2;                  // == __fmul_rn
                const float t2 = t1 * cff;                    // == __fmul_rn
                const float qf = (float)((double)t2 * invd);  // == __fdiv_rn(t2,total)
                const float vfl = floorf(qf);
                if (EDGE) {
                    const int wo = w0 + q - j;
                    const bool ok = rowok && (wo >= 0) && (wo < HO);
                    acc[q] += ok ? vfl : 0.f;
                } else {
                    acc[q] += vfl;
                }
            }
        }
    }
    float4 ov = make_float4(acc[0], acc[1], acc[2], acc[3]);
    *(float4*)(out + base + (size_t)h * WW + w0) = ov;
}

// interior: h in [2,189], w4 in [1,46] -> no clamps/masks anywhere.
__global__ __launch_bounds__(256) void out_interior(const float* __restrict__ x,
                                                    const float* __restrict__ pf,
                                                    const int* __restrict__ pi,
                                                    float* __restrict__ out)
{
    const int gid = blockIdx.x * 256 + threadIdx.x;
    const int w4i = gid % 46;
    int t = gid / 46;
    const int h = 2 + t % 188; t /= 188;
    const int ch = t & 255;
    const int b = t >> 8;
    motif_quad<false>(x, pf, pi, out, b, ch, h, (w4i + 1) * 4);
}

// edge: 568 quads per (b,ch): h in {0,1,190,191} x all 48 w4, plus
// h in [2,189] x w4 in {0,47}.
__global__ __launch_bounds__(256) void out_edge(const float* __restrict__ x,
                                                const float* __restrict__ pf,
                                                const int* __restrict__ pi,
                                                float* __restrict__ out)
{
    const int gid = blockIdx.x * 256 + threadIdx.x;
    const int e = gid % 568;
    int t = gid / 568;
    const int ch = t & 255;
    const int b = t >> 8;
    int h, w4;
    if (e < 192) {
        const int hs = e / 48;
        h = (hs < 2) ? hs : 188 + hs;         // 0,1,190,191
        w4 = e % 48;
    } else {
        const int e2 = e - 192;
        h = 2 + (e2 >> 1);
        w4 = (e2 & 1) ? 47 : 0;
    }
    motif_quad<true>(x, pf, pi, out, b, ch, h, w4 * 4);
}

// ---------------------------------------------------------------------------
extern "C" void kernel_launch(void* const* d_in, const int* in_sizes, int n_in,
                              void* d_out, int out_size, void* d_ws, size_t ws_size,
                              hipStream_t stream)
{
    const float* x = (const float*)d_in[0];
    float* out = (float*)d_out;

    double* gram = (double*)d_ws;
    const size_t gram_bytes = (size_t)32 * PP * PP * sizeof(double); // 5,308,416 B
    float* pf = (float*)((char*)d_ws + gram_bytes);
    int* pi = (int*)((char*)d_ws + gram_bytes + 256);

    gram_kernel<<<2304, 192, 0, stream>>>(x, gram);
    topk_kernel<<<16, 320, 0, stream>>>(gram, pf, pi);
    out_interior<<<17296, 256, 0, stream>>>(x, pf, pi, out);  // 2*256*188*46/256
    out_edge<<<1136, 256, 0, stream>>>(x, pf, pi, out);       // 2*256*568/256
}

// Round 15
// 350.324 us; speedup vs baseline: 1.3887x; 1.0393x over previous
//
#include <hip/hip_runtime.h>
#include <math.h>

// Problem constants
#define NB 2
#define NC 256
#define CG 16
#define HH 192
#define WW 192
#define HO 190
#define PP 144

typedef float v2f __attribute__((ext_vector_type(2)));

// LDS: 5684 floats = 22736 B -> 7 blocks/CU (was 29392 B -> 5).
// Band area: 29 rows x 49 float4-slots (196 floats/row: slots [0..3]=pads,
//   [4..195]=data, data col c at 4+c). Staged LINEARLY by global_load_lds;
//   pad-slot lanes load a harmless dup; pads re-zeroed after the drain.
//   Thread v's window = slots v+2..v+6; b64 reads at even base bb=(v+2)&~1.
// Epilogue: edge rows 0..11, row 12 = zero guard (0..2547);
//   red2[96][25] at 2548 (2548..4947); ebuf[2][25] at 4948.
#define SMEM_FLOATS 5684

#define GLD16(GP, LP)                                                         \
    __builtin_amdgcn_global_load_lds(                                         \
        (const __attribute__((address_space(1))) void*)(GP),                  \
        (__attribute__((address_space(3))) void*)(LP), 16, 0, 0)

// ---------------------------------------------------------------------------
// Kernel 1: correlation-decomposed Gram. Bit-identical gram vs rounds 1-14:
// u runs 2..189 sequentially with identical per-step FMA order; the reduce's
// first step (192->96) becomes a publish/merge pair computing the same
// cw_low + cw_high (IEEE add commutative bitwise).
// THIS ROUND: LDS diet for occupancy. 24-step bands (29-row area) +
// red2[96][25] two-phase reduce -> 22.7 KB -> 7 blocks/CU = 21 waves (was
// 5/15; r14 measured VALUBusy 43% = latency-bound). Low half recomputes cw
// at merge (no +25 VGPR). Staging = r14 winner: global_load_lds, linear
// dest, one drain/band. Compute = r12: dj-pair pk packing, b64 window
// reads, 6-phase pipelined ring, 6-deep global ring, XCD swizzle.
// ---------------------------------------------------------------------------
__global__ __launch_bounds__(192, 2) void gram_kernel(const float* __restrict__ x,
                                                      double* __restrict__ gram)
{
    __shared__ __align__(16) float smem[SMEM_FLOATS];
    float* const red2 = smem + 2548;          // [96][25]
    float* const ebuf = smem + 4948;          // [2][25]

    const int v = threadIdx.x;                // column 0..191
    const int p = v & 1;                      // window parity: dj = i - p
    const int bb = (v + 2) & ~1;              // even b64 base slot

    // XCD-clustered decode: bid%8 = intended XCD; half-group hg (36 blocks)
    // pinned to XCD hg%8. Bijective over 2304 blocks.
    const int bid = blockIdx.x;
    const int vx = bid & 7;
    const int tq = bid >> 3;                  // 0..287
    const int idxw = tq / 36;                 // 0..7
    const int rr0 = tq - idxw * 36;           // 0..35
    const int hg = idxw * 8 + vx;             // 0..63
    const int bg = hg >> 1;
    int r = rr0 + 36 * (hg & 1);              // 0..71
    int c2 = 0;
    while (r >= (c2 + 2) / 2) { r -= (c2 + 2) / 2; ++c2; }
    const int c1a = 2 * r;
    int c1b = 2 * r + 1;
    const bool bval = (c1b <= c2);
    if (!bval) c1b = c2;
    const int b = bg >> 4, g = bg & 15;

    const float* __restrict__ xa  = x + ((size_t)(b * NC + g * CG + c1a)) * (HH * WW);
    const float* __restrict__ xb  = x + ((size_t)(b * NC + g * CG + c1b)) * (HH * WW);
    const float* __restrict__ x2g = x + ((size_t)(b * NC + g * CG + c2 )) * (HH * WW);

    // accumulators: lanes = window positions (2*pr, 2*pr+1); dj = pos - p.
    v2f midA[15], midB[15];                   // [k*3 + pr]
#pragma unroll
    for (int o = 0; o < 15; ++o) { midA[o] = (v2f){0.f, 0.f}; midB[o] = (v2f){0.f, 0.f}; }

    v2f win[6][3];                            // slot s: local row L (L%6==s), 3 pairs
    float ca[6], cb[6];                       // ca[(u-2)%6] holds xa row u
#pragma unroll
    for (int k = 0; k < 6; ++k) {             // rows 2..7
        ca[k] = xa[(size_t)(2 + k) * WW + v];
        cb[k] = xb[(size_t)(2 + k) * WW + v];
    }

    const float* pa = xa + (size_t)8 * WW + v;   // refill base (row ubase+6)
    const float* pb = xb + (size_t)8 * WW + v;
    int lds_off;                              // float idx of WPF row b64 base

// One u-step. P = phase = LS%6 (compile-time). Consumes ca/cb[P] (row u) and
// win slots (P+kk)%6 (local rows LS..LS+4, loaded >=1 step earlier).
//   WPF: window row local LS+5 -> slot (P+5)%6: 3 x ds_read_b64;
//   GPF: ca/cb[P] <- rows at pa/pb[P*WW] (consumed 6 steps later).
#define USTEP6(P, WPF, GPF)                                                   \
    {                                                                         \
        const float a1 = ca[(P)];                                             \
        const float b1 = cb[(P)];                                             \
        if (GPF) { ca[(P)] = pa[(P) * WW]; cb[(P)] = pb[(P) * WW]; }          \
        if (WPF) {                                                            \
            _Pragma("unroll")                                                 \
            for (int pr = 0; pr < 3; ++pr)                                    \
                win[((P) + 5) % 6][pr] = *(const v2f*)(&smem[lds_off + 2 * pr]); \
        }                                                                     \
        lds_off += 196;                                                       \
        const v2f a2 = (v2f){a1, a1};                                         \
        const v2f b2 = (v2f){b1, b1};                                         \
        _Pragma("unroll")                                                     \
        for (int kk = 0; kk < 5; ++kk) {                                      \
            _Pragma("unroll")                                                 \
            for (int pr = 0; pr < 3; ++pr) {                                  \
                const v2f wv = win[((P) + kk) % 6][pr];                       \
                midA[kk * 3 + pr] = __builtin_elementwise_fma(a2, wv, midA[kk * 3 + pr]); \
                midB[kk * 3 + pr] = __builtin_elementwise_fma(b2, wv, midB[kk * 3 + pr]); \
            }                                                                 \
        }                                                                     \
    }

// Stage rows [ROW0, ...) linearly via global_load_lds (NROUND rounds, last
// round LASTN lanes); drain; re-zero pads of rows 0..28; barrier.
#define STAGE(ROW0, NROUND, LASTN)                                            \
    __syncthreads();                                                          \
    _Pragma("unroll")                                                         \
    for (int rr2 = 0; rr2 < (NROUND); ++rr2) {                                \
        if (rr2 < (NROUND) - 1 || v < (LASTN)) {                              \
            const int slot = rr2 * 192 + v;                                   \
            const int row = slot / 49;                                        \
            const int s49 = slot - row * 49;                                  \
            const int col = (s49 == 0) ? 0 : (s49 - 1) * 4;                   \
            const float* gp2 = x2g + (size_t)((ROW0) + row) * WW + col;       \
            float* lp = smem + (rr2 * 192 + (v & ~63)) * 4;                   \
            GLD16(gp2, lp);                                                   \
        }                                                                     \
    }                                                                         \
    __syncthreads();                                                          \
    if (v < 116) smem[(v >> 2) * 196 + (v & 3)] = 0.f;                        \
    __syncthreads();

    // 7 full bands x 24 steps (u=2..169, stage 29 rows = 1421 slots: 8
    // rounds, last 77) + 20-step tail (u=170..189, stage 24 rows = 1176
    // slots: 7 rounds, last 24). Step LS=23's WPF loads local 28 = next
    // band's local 4 (24%6==0 keeps ring slots aligned) -> bands chain;
    // only band 0 has a prologue.
    for (int band = 0; band < 7; ++band) {
        STAGE(band * 24, 8, 77)

        if (band == 0) {
#pragma unroll
            for (int k = 0; k < 5; ++k)
#pragma unroll
            for (int pr = 0; pr < 3; ++pr)
                win[k][pr] = *(const v2f*)(&smem[k * 196 + bb + 2 * pr]);
        }

        lds_off = 5 * 196 + bb;               // local row 5, this band
        for (int it = 0; it < 4; ++it) {      // rolled: small hot body
            USTEP6(0, 1, 1) USTEP6(1, 1, 1) USTEP6(2, 1, 1)
            USTEP6(3, 1, 1) USTEP6(4, 1, 1) USTEP6(5, 1, 1)
            pa += 6 * WW; pb += 6 * WW;       // next group's refill base
        }
    }
    // tail: u = 170..189 (LS 0..19), rows 168..191 at locals 0..23.
    STAGE(168, 7, 24)
    lds_off = 5 * 196 + bb;
    // LS 0..5 (u 170..175): GPF rows 176..181
    USTEP6(0, 1, 1) USTEP6(1, 1, 1) USTEP6(2, 1, 1)
    USTEP6(3, 1, 1) USTEP6(4, 1, 1) USTEP6(5, 1, 1)
    pa += 6 * WW; pb += 6 * WW;
    // LS 6..11 (u 176..181): GPF rows 182..187
    USTEP6(0, 1, 1) USTEP6(1, 1, 1) USTEP6(2, 1, 1)
    USTEP6(3, 1, 1) USTEP6(4, 1, 1) USTEP6(5, 1, 1)
    pa += 6 * WW; pb += 6 * WW;
    // LS 12..17 (u 182..187): GPF rows 188,189 only (LS<=13)
    USTEP6(0, 1, 1) USTEP6(1, 1, 1) USTEP6(2, 1, 0)
    USTEP6(3, 1, 0) USTEP6(4, 1, 0) USTEP6(5, 1, 0)
    // LS 18,19 (u 188,189): WPF local 23 at LS=18; none at LS=19
    USTEP6(0, 1, 0) USTEP6(1, 0, 0)
#undef USTEP6
#undef STAGE

    // stage edge buffer: buf i<6 -> abs row i-2 (OOB zero), i>=6 -> 188+(i-6).
    // Pads of rows 0..28 zero from tail re-zero; row 12 = zero guard.
    __syncthreads();
    for (int i = 0; i < 12; ++i) {
        const int ar = (i < 6) ? (i - 2) : (188 + i - 6);
        const float val = (ar >= 0 && ar <= 191) ? x2g[(size_t)ar * WW + v] : 0.f;
        smem[i * 196 + 4 + v] = val;
    }
    __syncthreads();

    double* const gp = gram + (size_t)bg * (PP * PP);

// cw for (k=KQ, dj=DJ) at runtime c=CVAL: mid (parity-selected) + edge-row
// corrections. Compile-time register indices; runtime select on p and CVAL.
#define EPI_CW(KQ, DJ, CVAL)                                                  \
    ({                                                                        \
        float ve_, vo_;                                                       \
        { const int pr_ = (DJ) >> 1, ln_ = (DJ) & 1;                          \
          const v2f m_ = ((CVAL) == 0) ? midA[(KQ) * 3 + pr_] : midB[(KQ) * 3 + pr_]; \
          ve_ = ln_ ? m_.y : m_.x; }                                          \
        { const int pr_ = ((DJ) + 1) >> 1, ln_ = ((DJ) + 1) & 1;              \
          const v2f m_ = ((CVAL) == 0) ? midA[(KQ) * 3 + pr_] : midB[(KQ) * 3 + pr_]; \
          vo_ = ln_ ? m_.y : m_.x; }                                          \
        float cw_ = p ? vo_ : ve_;                                            \
        cw_ = fmaf(xra, smem[bufa * 196 + 2 + v + (DJ)], cw_);                \
        cw_ = fmaf(xrb, smem[bufb * 196 + 2 + v + (DJ)], cw_);                \
        cw_;                                                                  \
    })

#pragma unroll
    for (int i1 = 0; i1 < 3; ++i1) {
        const int ra = (i1 == 0) ? 0 : ((i1 == 1) ? 1 : 190);
        const int rb = (i1 == 0) ? 1 : ((i1 == 1) ? 190 : 191);
#pragma unroll
        for (int c = 0; c < 2; ++c) {
            const float* __restrict__ xc = (c == 0) ? xa : xb;
            const float xra = xc[(size_t)ra * WW + v];
            const float xrb = xc[(size_t)rb * WW + v];
            // publish: high half -> red2 rows 0..95; threads 0,1 -> ebuf
            if (v >= 96) {
#pragma unroll
                for (int k = 0; k < 5; ++k) {
                    const int bufa = (ra < 2) ? (ra + k) : (ra + k - 184);
                    const int bufb = (rb < 2) ? (rb + k) : (rb + k - 184);
#pragma unroll
                    for (int dj = 0; dj < 5; ++dj)
                        red2[(v - 96) * 25 + k * 5 + dj] = EPI_CW(k, dj, c);
                }
            } else if (v < 2) {
#pragma unroll
                for (int k = 0; k < 5; ++k) {
                    const int bufa = (ra < 2) ? (ra + k) : (ra + k - 184);
                    const int bufb = (rb < 2) ? (rb + k) : (rb + k - 184);
#pragma unroll
                    for (int dj = 0; dj < 5; ++dj)
                        ebuf[v * 25 + k * 5 + dj] = EPI_CW(k, dj, c);
                }
            }
            __syncthreads();
            float e0 = 0.f, e1 = 0.f, e190 = 0.f, e191 = 0.f;
            if (v < 25) {
                e0   = ebuf[v];
                e1   = ebuf[25 + v];
                e190 = red2[94 * 25 + v];
                e191 = red2[95 * 25 + v];
            }
            __syncthreads();
            // merge (== old s=96 step): red2[v] = cw_high + cw_low
            if (v < 96) {
#pragma unroll
                for (int k = 0; k < 5; ++k) {
                    const int bufa = (ra < 2) ? (ra + k) : (ra + k - 184);
                    const int bufb = (rb < 2) ? (rb + k) : (rb + k - 184);
#pragma unroll
                    for (int dj = 0; dj < 5; ++dj)
                        red2[v * 25 + k * 5 + dj] += EPI_CW(k, dj, c);
                }
            }
            __syncthreads();
            // tree reduce: 96 -> 48 -> ... -> 3 (stride 25: conflict-free)
#pragma unroll
            for (int s = 48; s >= 3; s >>= 1) {
                for (int idx = v; idx < s * 25; idx += 192) {
                    const int vv = idx / 25, o = idx - vv * 25;
                    red2[vv * 25 + o] += red2[(vv + s) * 25 + o];
                }
                __syncthreads();
            }
            if (v < 25 && (c == 0 || bval)) {
                const int di = v / 5 - 2, dj = v - (v / 5) * 5 - 2;
                const int i2 = i1 + di;
                if (i2 >= 0 && i2 <= 2) {
                    const float S = red2[0 * 25 + v] + red2[1 * 25 + v] + red2[2 * 25 + v];
                    const int c1 = (c == 0) ? c1a : c1b;
#pragma unroll
                    for (int j1 = 0; j1 < 3; ++j1) {
                        const int j2 = j1 + dj;
                        if (j2 < 0 || j2 > 2) continue;
                        const float W = S - ((j1 == 0) ? (e190 + e191)
                                          : (j1 == 1) ? (e0 + e191)
                                                      : (e0 + e1));
                        const int pp = c1 * 9 + i1 * 3 + j1;
                        const int qq = c2 * 9 + i2 * 3 + j2;
                        gp[pp * PP + qq] = (double)W;
                        if (c1 != c2) gp[qq * PP + pp] = (double)W;
                    }
                }
            }
            __syncthreads();   // red2 reused by next (i1,c)
        }
    }
#undef EPI_CW
}

// ---------------------------------------------------------------------------
// Kernel 2: per-group argmin (f64 d2, first-min tiebreak), bincount over both
// batches, stable top-3 (smallest index on count ties, matching lax.top_k).
// ---------------------------------------------------------------------------
__global__ __launch_bounds__(320) void topk_kernel(const double* __restrict__ gram,
                                                   float* __restrict__ pf,
                                                   int* __restrict__ pi)
{
    const int g = blockIdx.x;
    __shared__ double sdiag[2][PP];
    __shared__ int counts[PP];
    const int tid = threadIdx.x;
    if (tid < PP) counts[tid] = 0;
    if (tid < 2 * PP) {
        const int b = tid / PP, p = tid % PP;
        const double* gb = gram + (size_t)(b * 16 + g) * (PP * PP);
        sdiag[b][p] = gb[p * PP + p];
    }
    __syncthreads();
    if (tid < 2 * PP) {
        const int b = tid / PP, p = tid % PP;
        const double* row = gram + ((size_t)(b * 16 + g) * PP + p) * PP;
        const double sp = sdiag[b][p];
        double best = 1e300;
        int bi = 0;
        for (int q = 0; q < PP; ++q) {
            if (q == p) continue;
            const double d2 = sp + sdiag[b][q] - 2.0 * row[q];
            if (d2 < best) { best = d2; bi = q; }   // strict < : first occurrence
        }
        atomicAdd(&counts[bi], 1);
    }
    __syncthreads();
    if (tid == 0) {
        int sel[3], cv[3];
        for (int o = 0; o < 3; ++o) {
            int bc = -1, bp = 0;
            for (int p = 0; p < PP; ++p) {
                bool taken = false;
                for (int u = 0; u < o; ++u) if (sel[u] == p) taken = true;
                if (!taken && counts[p] > bc) { bc = counts[p]; bp = p; } // > keeps lowest idx
            }
            sel[o] = bp; cv[o] = bc;
        }
        const int tot = cv[0] + cv[1] + cv[2];
        for (int o = 0; o < 3; ++o) {
            pf[g * 4 + o] = (float)cv[o];
            pi[g * 4 + o] = sel[o];
        }
        pf[g * 4 + 3] = (float)tot;
    }
}

// ---------------------------------------------------------------------------
// Kernel 3: fused scale->floor->fold stencil. t1,t2 = plain f32 muls
// (== __fmul_rn == reference). Division via Markstein 2-fma refinement:
//   rcp = RN32(1/total)  [f64 path; double-rounding safe: 1/total is
//         >=2^-34 rel from any f32 midpoint, f64 error <=2^-53]
//   q0 = t2*rcp; r = fma(-total,q0,t2); qf = fma(r,rcp,q0)
// qf == __fdiv_rn(t2,total): pre-round error ~2^-47 rel, exact quotients
// are >=2^-34 rel from any f32 midpoint (total<=288, t2 24-bit mantissa;
// exact-midpoint impossible: would need 25-bit odd factor in a <2^24 int).
// All operands stay normal (|t2| >= ~2^-66 given input quantization).
// Interior/edge split by BLOCK range in ONE kernel (branch block-uniform).
// ---------------------------------------------------------------------------
template <bool EDGE>
__device__ __forceinline__ void motif_quad(const float* __restrict__ x,
                                           const float* __restrict__ pf,
                                           const int* __restrict__ pi,
                                           float* __restrict__ out,
                                           int b, int ch, int h, int w0)
{
    const int g = ch >> 4;
    const size_t base = ((size_t)(b * NC + ch)) * (HH * WW);
    const float4 xv4 = *(const float4*)(x + base + (size_t)h * WW + w0);
    const float xs[4] = {xv4.x, xv4.y, xv4.z, xv4.w};
    float acc[4] = {0.f, 0.f, 0.f, 0.f};
    const float total = pf[g * 4 + 3];
    const float rcp = (float)(1.0 / (double)total);   // == RN32(1/total)

#pragma unroll
    for (int o = 0; o < 3; ++o) {
        const int p = pi[g * 4 + o];
        const float cff = pf[g * 4 + o];
        const int co = p / 9;
        const int kk = p - co * 9;
        const int io = kk / 3, jo = kk - (kk / 3) * 3;
        const float* Rb = x + ((size_t)(b * NC + g * CG + co)) * (HH * WW);
#pragma unroll
        for (int i = 0; i < 3; ++i) {
            const int ho = h - i;
            bool rowok = true;
            int hr = ho + io;
            if (EDGE) {
                rowok = (ho >= 0) && (ho < HO);
                hr = hr < 0 ? 0 : (hr > HH - 1 ? HH - 1 : hr);
            }
            const float* row = Rb + (size_t)hr * WW;
            float rv[6];
#pragma unroll
            for (int u = 0; u < 6; ++u) {
                int col = w0 - 2 + jo + u;
                if (EDGE) col = col < 0 ? 0 : (col > WW - 1 ? WW - 1 : col);
                rv[u] = row[col];
            }
#pragma unroll
            for (int j = 0; j < 3; ++j)
#pragma unroll
            for (int q = 0; q < 4; ++q) {
                const float r2 = rv[q - j + 2];
                const float t1 = xs[q] * r2;              // == __fmul_rn
                const float t2 = t1 * cff;                // == __fmul_rn
                const float q0 = t2 * rcp;
                const float rr = fmaf(-total, q0, t2);
                const float qf = fmaf(rr, rcp, q0);       // == __fdiv_rn(t2,total)
                const float vfl = floorf(qf);
                if (EDGE) {
                    const int wo = w0 + q - j;
                    const bool ok = rowok && (wo >= 0) && (wo < HO);
                    acc[q] += ok ? vfl : 0.f;
                } else {
                    acc[q] += vfl;
                }
            }
        }
    }
    float4 ov = make_float4(acc[0], acc[1], acc[2], acc[3]);
    *(float4*)(out + base + (size_t)h * WW + w0) = ov;
}

#define NBLK_INT 17296   // 2*256*188*46/256
#define NBLK_EDGE 1136   // 2*256*568/256

__global__ __launch_bounds__(256) void out_kernel(const float* __restrict__ x,
                                                  const float* __restrict__ pf,
                                                  const int* __restrict__ pi,
                                                  float* __restrict__ out)
{
    const int bid = blockIdx.x;
    if (bid < NBLK_INT) {
        // interior: h in [2,189], w4 in [1,46] -> no clamps/masks anywhere.
        const int gid = bid * 256 + threadIdx.x;
        const int w4i = gid % 46;
        int t = gid / 46;
        const int h = 2 + t % 188; t /= 188;
        const int ch = t & 255;
        const int b = t >> 8;
        motif_quad<false>(x, pf, pi, out, b, ch, h, (w4i + 1) * 4);
    } else {
        // edge: 568 quads per (b,ch): h in {0,1,190,191} x all 48 w4, plus
        // h in [2,189] x w4 in {0,47}.
        const int gid = (bid - NBLK_INT) * 256 + threadIdx.x;
        const int e = gid % 568;
        int t = gid / 568;
        const int ch = t & 255;
        const int b = t >> 8;
        int h, w4;
        if (e < 192) {
            const int hs = e / 48;
            h = (hs < 2) ? hs : 188 + hs;     // 0,1,190,191
            w4 = e % 48;
        } else {
            const int e2 = e - 192;
            h = 2 + (e2 >> 1);
            w4 = (e2 & 1) ? 47 : 0;
        }
        motif_quad<true>(x, pf, pi, out, b, ch, h, w4 * 4);
    }
}

// ---------------------------------------------------------------------------
extern "C" void kernel_launch(void* const* d_in, const int* in_sizes, int n_in,
                              void* d_out, int out_size, void* d_ws, size_t ws_size,
                              hipStream_t stream)
{
    const float* x = (const float*)d_in[0];
    float* out = (float*)d_out;

    double* gram = (double*)d_ws;
    const size_t gram_bytes = (size_t)32 * PP * PP * sizeof(double); // 5,308,416 B
    float* pf = (float*)((char*)d_ws + gram_bytes);
    int* pi = (int*)((char*)d_ws + gram_bytes + 256);

    gram_kernel<<<2304, 192, 0, stream>>>(x, gram);
    topk_kernel<<<16, 320, 0, stream>>>(gram, pf, pi);
    out_kernel<<<NBLK_INT + NBLK_EDGE, 256, 0, stream>>>(x, pf, pi, out);
}